// Round 3
// baseline (114340.271 us; speedup 1.0000x reference)
//
#include <hip/hip_runtime.h>
#include <cstdint>
#include <cstddef>

#define B_ 32
#define L_ 1024
#define I_ 1024
#define H_ 1024
#define G3_ 3072
#define G3I ((size_t)G3_ * I_)
#define NBLK 256

typedef short short8 __attribute__((ext_vector_type(8)));
typedef float floatx4 __attribute__((ext_vector_type(4)));

__device__ __forceinline__ unsigned short f2bf_rne(float f) {
    unsigned u = __float_as_uint(f);
    unsigned r = (u + 0x7fffu + ((u >> 16) & 1u)) >> 16;
    return (unsigned short)r;
}
__device__ __forceinline__ float bf2f(unsigned short u) {
    return __uint_as_float(((unsigned)u) << 16);
}

// ---- prep: transpose weights [K][3H] -> [col][K], split bf16 hi/lo ---------
// wt layout: mat in {Wi0,Wh0,Wi1,Wh1}: base = mat*2*G3I ; hi then lo (G3I each)
__global__ __launch_bounds__(256) void k_trans_w(const float* __restrict__ Wi,
                                                 const float* __restrict__ Wh,
                                                 unsigned short* __restrict__ wt) {
    int mat = blockIdx.y;            // 0=Wi0 1=Wh0 2=Wi1 3=Wh1
    int layer = mat >> 1, ish = mat & 1;
    const float* src = (ish ? Wh : Wi) + (size_t)layer * I_ * G3_;
    unsigned short* dhi = wt + (size_t)mat * 2u * G3I;
    unsigned short* dlo = dhi + G3I;
    int kt = blockIdx.x & 15;        // 16 k-tiles of 64
    int ct = blockIdx.x >> 4;        // 48 col-tiles of 64
    __shared__ float tile[64][65];
    int tid = threadIdx.x;
    int c_in = tid & 63, kr = tid >> 6;
    for (int pass = 0; pass < 16; ++pass) {
        int k = kt * 64 + pass * 4 + kr;
        tile[pass * 4 + kr][c_in] = src[(size_t)k * G3_ + ct * 64 + c_in];
    }
    __syncthreads();
    int k_out = tid & 63, cr = tid >> 6;
    for (int pass = 0; pass < 16; ++pass) {
        int c = ct * 64 + pass * 4 + cr;
        float f = tile[k_out][pass * 4 + cr];
        unsigned short hb = f2bf_rne(f);
        size_t o = (size_t)c * I_ + kt * 64 + k_out;
        dhi[o] = hb;
        dlo[o] = f2bf_rne(f - bf2f(hb));
    }
}

// ---- precompute gi0 = x @ Wi0 for ALL timesteps (one big GEMM) -------------
__global__ __launch_bounds__(512) void k_gi0(const float* __restrict__ xf,
                                             const unsigned short* __restrict__ wt,
                                             float* __restrict__ gi0) {
    int mt = blockIdx.x;             // 512 m-tiles of 64 rows
    int nt = blockIdx.y;             // 48 n-tiles of 64 cols
    int tid = threadIdx.x, wave = tid >> 6, lane = tid & 63;
    int mq = wave & 3, npair = wave >> 2;
    int arow = lane & 15, klq = (lane >> 4) * 8;
    const unsigned short* wHi = wt;  // Wi0 hi
    const unsigned short* wLo = wt + G3I;
    size_t abase = ((size_t)(mt * 64 + mq * 16 + arow)) * I_;
    int c0 = nt * 64 + npair * 32 + (lane & 15);
    floatx4 acc[2] = {};
    for (int it = 0; it < 32; ++it) {
        int kk = it * 32 + klq;
        float4 f0 = *(const float4*)(xf + abase + kk);
        float4 f1 = *(const float4*)(xf + abase + kk + 4);
        short8 ah, al;
        {
            float v0 = f0.x, v1 = f0.y, v2 = f0.z, v3 = f0.w;
            float v4 = f1.x, v5 = f1.y, v6 = f1.z, v7 = f1.w;
            unsigned short hb;
            hb = f2bf_rne(v0); ah[0] = (short)hb; al[0] = (short)f2bf_rne(v0 - bf2f(hb));
            hb = f2bf_rne(v1); ah[1] = (short)hb; al[1] = (short)f2bf_rne(v1 - bf2f(hb));
            hb = f2bf_rne(v2); ah[2] = (short)hb; al[2] = (short)f2bf_rne(v2 - bf2f(hb));
            hb = f2bf_rne(v3); ah[3] = (short)hb; al[3] = (short)f2bf_rne(v3 - bf2f(hb));
            hb = f2bf_rne(v4); ah[4] = (short)hb; al[4] = (short)f2bf_rne(v4 - bf2f(hb));
            hb = f2bf_rne(v5); ah[5] = (short)hb; al[5] = (short)f2bf_rne(v5 - bf2f(hb));
            hb = f2bf_rne(v6); ah[6] = (short)hb; al[6] = (short)f2bf_rne(v6 - bf2f(hb));
            hb = f2bf_rne(v7); ah[7] = (short)hb; al[7] = (short)f2bf_rne(v7 - bf2f(hb));
        }
#pragma unroll
        for (int n = 0; n < 2; ++n) {
            size_t bo = (size_t)(c0 + n * 16) * I_ + kk;
            short8 bh_ = *(const short8*)(wHi + bo);
            short8 bl_ = *(const short8*)(wLo + bo);
            acc[n] = __builtin_amdgcn_mfma_f32_16x16x32_bf16(ah, bh_, acc[n], 0, 0, 0);
            acc[n] = __builtin_amdgcn_mfma_f32_16x16x32_bf16(ah, bl_, acc[n], 0, 0, 0);
            acc[n] = __builtin_amdgcn_mfma_f32_16x16x32_bf16(al, bh_, acc[n], 0, 0, 0);
        }
    }
#pragma unroll
    for (int n = 0; n < 2; ++n)
#pragma unroll
        for (int r = 0; r < 4; ++r) {
            int rr = mt * 64 + mq * 16 + (lane >> 4) * 4 + r;
            int b = rr >> 10, t = rr & 1023;
            gi0[((size_t)t * B_ + b) * G3_ + c0 + n * 16] = acc[n][r];
        }
}

// ---- persistent GRU kernel --------------------------------------------------
// 256 blocks x 512 thr, 1 block/CU. Block grp owns units [grp*4, grp*4+4).
// Weights for its 9 needed columns x 3 mats (Wh0, Wi1, Wh1) hi/lo live in LDS
// for the whole sequence (144KB, XOR-swizzled to avoid bank conflicts).
// Per step: MFMA gh0/gi1/gh1 (k split over 8 waves, reduced via LDS atomicAdd),
// act threads apply GRU cell (h_prev in registers), publish bf16 hi/lo state,
// then a monotonic-counter grid barrier (release/acquire via __threadfence).
__global__ __launch_bounds__(512, 2) void k_gru_pers(
    const unsigned short* __restrict__ wt,
    const float* __restrict__ gi0,
    const float* __restrict__ b_i, const float* __restrict__ b_h,
    unsigned short* __restrict__ hst,
    unsigned int* __restrict__ bar,
    float* __restrict__ out) {

    __shared__ unsigned short wlds[73728];  // 72 col-entries x 1024 shorts = 144KB
    __shared__ float red[3][32][16];        // 6KB summed partials

    const int grp = blockIdx.x;
    const int tid = threadIdx.x, wave = tid >> 6, lane = tid & 63;

    // ---- stage weight slice into LDS (once) --------------------------------
    // entry e = (m*2+p)*12 + cl ; m: 0=Wh0(mat1) 1=Wi1(mat2) 2=Wh1(mat3); p: hi/lo
    for (int idx = tid; idx < 72 * 128; idx += 512) {
        int e = idx >> 7, chunk = idx & 127;
        int mp = e / 12, cle = e % 12;
        int m = mp >> 1, p = mp & 1;
        size_t gcol = (size_t)((cle >> 2) * H_ + grp * 4 + (cle & 3));
        const unsigned short* src = wt + (size_t)(m + 1) * 2 * G3I + (size_t)p * G3I
                                       + gcol * I_ + (size_t)chunk * 8;
        short8 v = *(const short8*)src;
        int byteoff = (e * 2048 + chunk * 16) ^ ((cle & 7) << 4);
        *(short8*)((char*)wlds + byteoff) = v;
    }

    // per-lane MFMA constants
    const int arow = lane & 15;
    const int c = lane & 15;
    const int cl = (c < 12) ? c : c - 4;      // lanes 12-15 duplicate n-gate cols
    const int xm = (cl & 7) << 4;
    int wb[6];
#pragma unroll
    for (int mp = 0; mp < 6; ++mp) wb[mp] = (mp * 12 + cl) * 2048;

    // act-thread setup: tid<128 -> layer0 act, 128..255 -> layer1 act
    const int bact = (tid & 127) >> 2, uu = tid & 3;
    const int u = grp * 4 + uu;
    float bir = 0.f, biz = 0.f, bin = 0.f, bhr = 0.f, bhz = 0.f, bhn = 0.f;
    if (tid < 256) {
        int ly = (tid < 128) ? 0 : 1;
        const float* bi = b_i + (size_t)ly * G3_;
        const float* bh = b_h + (size_t)ly * G3_;
        bir = bi[u]; biz = bi[H_ + u]; bin = bi[2 * H_ + u];
        bhr = bh[u]; bhz = bh[H_ + u]; bhn = bh[2 * H_ + u];
    }
    float hp = 0.f;   // register-resident h_prev for this thread's (b,u)

    __syncthreads();

    for (int s = 0; s <= L_; ++s) {
        // prefetch gi0 for this step (latency hides under MFMA phase)
        float g0r = 0.f, g0z = 0.f, g0n = 0.f;
        if (tid < 128 && s < L_) {
            const float* gsrc = gi0 + ((size_t)s * B_ + bact) * G3_;
            g0r = gsrc[u]; g0z = gsrc[H_ + u]; g0n = gsrc[2 * H_ + u];
        }

        // zero reduction buffer
        for (int i = tid; i < 3 * 32 * 16; i += 512) ((float*)red)[i] = 0.f;
        __syncthreads();

        const int rd0 = (s - 1) & 1;     // slot of h0[s-1]
        const int rd1 = s & 1;           // slot of h1[s-2]
        const unsigned short* a0h = hst + (size_t)(0 + rd0) * 32768;
        const unsigned short* a0l = hst + (size_t)(2 + rd0) * 32768;
        const unsigned short* a1h = hst + (size_t)(4 + rd1) * 32768;
        const unsigned short* a1l = hst + (size_t)(6 + rd1) * 32768;
        const char* wbase = (const char*)wlds;

        floatx4 acc[3][2] = {};
#pragma unroll
        for (int ks = 0; ks < 4; ++ks) {
            const int kk = wave * 128 + (lane >> 4) * 8 + ks * 32;  // shorts
            const int kb = kk * 2;                                   // bytes
            short8 p0h = *(const short8*)(a0h + (size_t)arow * I_ + kk);
            short8 p0l = *(const short8*)(a0l + (size_t)arow * I_ + kk);
            short8 p1h = *(const short8*)(a0h + (size_t)(16 + arow) * I_ + kk);
            short8 p1l = *(const short8*)(a0l + (size_t)(16 + arow) * I_ + kk);
            short8 q0h = *(const short8*)(a1h + (size_t)arow * I_ + kk);
            short8 q0l = *(const short8*)(a1l + (size_t)arow * I_ + kk);
            short8 q1h = *(const short8*)(a1h + (size_t)(16 + arow) * I_ + kk);
            short8 q1l = *(const short8*)(a1l + (size_t)(16 + arow) * I_ + kk);
            short8 u1h = *(const short8*)(wbase + ((wb[0] + kb) ^ xm));
            short8 u1l = *(const short8*)(wbase + ((wb[1] + kb) ^ xm));
            short8 u2h = *(const short8*)(wbase + ((wb[2] + kb) ^ xm));
            short8 u2l = *(const short8*)(wbase + ((wb[3] + kb) ^ xm));
            short8 u3h = *(const short8*)(wbase + ((wb[4] + kb) ^ xm));
            short8 u3l = *(const short8*)(wbase + ((wb[5] + kb) ^ xm));
            acc[0][0] = __builtin_amdgcn_mfma_f32_16x16x32_bf16(p0h, u1h, acc[0][0], 0, 0, 0);
            acc[0][0] = __builtin_amdgcn_mfma_f32_16x16x32_bf16(p0h, u1l, acc[0][0], 0, 0, 0);
            acc[0][0] = __builtin_amdgcn_mfma_f32_16x16x32_bf16(p0l, u1h, acc[0][0], 0, 0, 0);
            acc[0][1] = __builtin_amdgcn_mfma_f32_16x16x32_bf16(p1h, u1h, acc[0][1], 0, 0, 0);
            acc[0][1] = __builtin_amdgcn_mfma_f32_16x16x32_bf16(p1h, u1l, acc[0][1], 0, 0, 0);
            acc[0][1] = __builtin_amdgcn_mfma_f32_16x16x32_bf16(p1l, u1h, acc[0][1], 0, 0, 0);
            acc[1][0] = __builtin_amdgcn_mfma_f32_16x16x32_bf16(p0h, u2h, acc[1][0], 0, 0, 0);
            acc[1][0] = __builtin_amdgcn_mfma_f32_16x16x32_bf16(p0h, u2l, acc[1][0], 0, 0, 0);
            acc[1][0] = __builtin_amdgcn_mfma_f32_16x16x32_bf16(p0l, u2h, acc[1][0], 0, 0, 0);
            acc[1][1] = __builtin_amdgcn_mfma_f32_16x16x32_bf16(p1h, u2h, acc[1][1], 0, 0, 0);
            acc[1][1] = __builtin_amdgcn_mfma_f32_16x16x32_bf16(p1h, u2l, acc[1][1], 0, 0, 0);
            acc[1][1] = __builtin_amdgcn_mfma_f32_16x16x32_bf16(p1l, u2h, acc[1][1], 0, 0, 0);
            acc[2][0] = __builtin_amdgcn_mfma_f32_16x16x32_bf16(q0h, u3h, acc[2][0], 0, 0, 0);
            acc[2][0] = __builtin_amdgcn_mfma_f32_16x16x32_bf16(q0h, u3l, acc[2][0], 0, 0, 0);
            acc[2][0] = __builtin_amdgcn_mfma_f32_16x16x32_bf16(q0l, u3h, acc[2][0], 0, 0, 0);
            acc[2][1] = __builtin_amdgcn_mfma_f32_16x16x32_bf16(q1h, u3h, acc[2][1], 0, 0, 0);
            acc[2][1] = __builtin_amdgcn_mfma_f32_16x16x32_bf16(q1h, u3l, acc[2][1], 0, 0, 0);
            acc[2][1] = __builtin_amdgcn_mfma_f32_16x16x32_bf16(q1l, u3h, acc[2][1], 0, 0, 0);
        }

        // cross-wave reduce via LDS atomics (dup lanes 12-15 hit unused cols 12-15)
#pragma unroll
        for (int m = 0; m < 3; ++m)
#pragma unroll
            for (int mm = 0; mm < 2; ++mm)
#pragma unroll
                for (int r = 0; r < 4; ++r)
                    atomicAdd(&red[m][mm * 16 + (lane >> 4) * 4 + r][c], acc[m][mm][r]);
        __syncthreads();

        // ---- epilogue -------------------------------------------------------
        if (tid < 128) {
            if (s < L_) {
                float sr = red[0][bact][uu];
                float sz = red[0][bact][4 + uu];
                float sn = red[0][bact][8 + uu];
                float vr = g0r + bir + sr + bhr;
                float vz = g0z + biz + sz + bhz;
                float r_ = 1.f / (1.f + __expf(-vr));
                float z_ = 1.f / (1.f + __expf(-vz));
                float ht = tanhf(g0n + bin + r_ * (sn + bhn));
                float hn = z_ * hp + (1.f - z_) * ht;
                hp = hn;
                int wr_ = s & 1;
                unsigned short hb16 = f2bf_rne(hn);
                hst[(size_t)(0 + wr_) * 32768 + bact * H_ + u] = hb16;
                hst[(size_t)(2 + wr_) * 32768 + bact * H_ + u] = f2bf_rne(hn - bf2f(hb16));
                if (s == L_ - 1) out[(size_t)B_ * L_ * H_ + bact * H_ + u] = hn;
            }
        } else if (tid < 256) {
            if (s >= 1) {
                int t = s - 1;
                float gr = red[1][bact][uu];
                float gz = red[1][bact][4 + uu];
                float gn = red[1][bact][8 + uu];
                float hr = red[2][bact][uu];
                float hz = red[2][bact][4 + uu];
                float hn_ = red[2][bact][8 + uu];
                float vr = gr + bir + hr + bhr;
                float vz = gz + biz + hz + bhz;
                float r_ = 1.f / (1.f + __expf(-vr));
                float z_ = 1.f / (1.f + __expf(-vz));
                float ht = tanhf(gn + bin + r_ * (hn_ + bhn));
                float hnv = z_ * hp + (1.f - z_) * ht;
                hp = hnv;
                int wr1 = (s - 1) & 1;
                unsigned short hb16 = f2bf_rne(hnv);
                hst[(size_t)(4 + wr1) * 32768 + bact * H_ + u] = hb16;
                hst[(size_t)(6 + wr1) * 32768 + bact * H_ + u] = f2bf_rne(hnv - bf2f(hb16));
                out[((size_t)bact * L_ + t) * H_ + u] = hnv;
                if (t == L_ - 1)
                    out[(size_t)B_ * L_ * H_ + (size_t)B_ * H_ + bact * H_ + u] = hnv;
            }
        }

        // ---- grid barrier (monotonic counter, release/acquire) --------------
        __threadfence();                 // release: flush state stores to L3
        __syncthreads();
        if (tid == 0) {
            __hip_atomic_fetch_add(bar, 1u, __ATOMIC_RELAXED, __HIP_MEMORY_SCOPE_AGENT);
            unsigned tgt = (unsigned)(s + 1) * NBLK;
            while (__hip_atomic_load(bar, __ATOMIC_RELAXED, __HIP_MEMORY_SCOPE_AGENT) < tgt)
                __builtin_amdgcn_s_sleep(1);
        }
        __syncthreads();
        __threadfence();                 // acquire: invalidate L1/L2 before state reads
    }
}

extern "C" void kernel_launch(void* const* d_in, const int* in_sizes, int n_in,
                              void* d_out, int out_size, void* d_ws, size_t ws_size,
                              hipStream_t stream) {
    const float* x  = (const float*)d_in[0];
    const float* Wi = (const float*)d_in[1];
    const float* bi = (const float*)d_in[2];
    const float* Wh = (const float*)d_in[3];
    const float* bh = (const float*)d_in[4];
    float* out = (float*)d_out;
    char* ws = (char*)d_ws;

    // ws layout (bytes):
    //  [0, 48MB)              wt: 4 mats x {hi,lo} x [3072][1024] bf16
    //  [50331648, +512KB)     hst: 4 bufs x 2 slots x 32768 bf16
    //  [50855936, +4KB)       bar: grid barrier counter
    //  [51380224, +384MB)     gi0: f32 [L][B][3H]
    unsigned short* wt  = (unsigned short*)(ws);
    unsigned short* hst = (unsigned short*)(ws + 50331648);
    unsigned int*   bar = (unsigned int*)(ws + 50855936);
    float*          gi0 = (float*)(ws + 51380224);

    hipMemsetAsync(ws + 50331648, 0, 1048576, stream);
    k_trans_w<<<dim3(768, 4), 256, 0, stream>>>(Wi, Wh, wt);
    k_gi0<<<dim3(512, 48), 512, 0, stream>>>(x, wt, gi0);

    void* args[] = {&wt, &gi0, &bi, &bh, &hst, &bar, &out};
    hipLaunchCooperativeKernel((void*)k_gru_pers, dim3(NBLK), dim3(512), args, 0, stream);
}

// Round 4
// 39668.845 us; speedup vs baseline: 2.8824x; 2.8824x over previous
//
#include <hip/hip_runtime.h>
#include <cstdint>
#include <cstddef>

#define B_ 32
#define L_ 1024
#define I_ 1024
#define H_ 1024
#define G3_ 3072
#define G3I ((size_t)G3_ * I_)
#define NBLK 256

typedef short short8 __attribute__((ext_vector_type(8)));
typedef float floatx4 __attribute__((ext_vector_type(4)));

__device__ __forceinline__ unsigned short f2bf_rne(float f) {
    unsigned u = __float_as_uint(f);
    unsigned r = (u + 0x7fffu + ((u >> 16) & 1u)) >> 16;
    return (unsigned short)r;
}
__device__ __forceinline__ float bf2f(unsigned short u) {
    return __uint_as_float(((unsigned)u) << 16);
}

// agent-scope (coherence-point) 16B read as two 8B atomic loads; k-contiguous
__device__ __forceinline__ short8 ld16_agent(const unsigned short* p) {
    unsigned long long q0 = __hip_atomic_load((unsigned long long*)p,
                                              __ATOMIC_RELAXED, __HIP_MEMORY_SCOPE_AGENT);
    unsigned long long q1 = __hip_atomic_load((unsigned long long*)p + 1,
                                              __ATOMIC_RELAXED, __HIP_MEMORY_SCOPE_AGENT);
    union { unsigned long long q[2]; short8 s; } u;
    u.q[0] = q0; u.q[1] = q1;
    return u.s;
}

// ---- prep: transpose weights [K][3H] -> [col][K], split bf16 hi/lo ---------
__global__ __launch_bounds__(256) void k_trans_w(const float* __restrict__ Wi,
                                                 const float* __restrict__ Wh,
                                                 unsigned short* __restrict__ wt) {
    int mat = blockIdx.y;            // 0=Wi0 1=Wh0 2=Wi1 3=Wh1
    int layer = mat >> 1, ish = mat & 1;
    const float* src = (ish ? Wh : Wi) + (size_t)layer * I_ * G3_;
    unsigned short* dhi = wt + (size_t)mat * 2u * G3I;
    unsigned short* dlo = dhi + G3I;
    int kt = blockIdx.x & 15;        // 16 k-tiles of 64
    int ct = blockIdx.x >> 4;        // 48 col-tiles of 64
    __shared__ float tile[64][65];
    int tid = threadIdx.x;
    int c_in = tid & 63, kr = tid >> 6;
    for (int pass = 0; pass < 16; ++pass) {
        int k = kt * 64 + pass * 4 + kr;
        tile[pass * 4 + kr][c_in] = src[(size_t)k * G3_ + ct * 64 + c_in];
    }
    __syncthreads();
    int k_out = tid & 63, cr = tid >> 6;
    for (int pass = 0; pass < 16; ++pass) {
        int c = ct * 64 + pass * 4 + cr;
        float f = tile[k_out][pass * 4 + cr];
        unsigned short hb = f2bf_rne(f);
        size_t o = (size_t)c * I_ + kt * 64 + k_out;
        dhi[o] = hb;
        dlo[o] = f2bf_rne(f - bf2f(hb));
    }
}

// ---- precompute gi0 = x @ Wi0 for ALL timesteps (one big GEMM) -------------
__global__ __launch_bounds__(512) void k_gi0(const float* __restrict__ xf,
                                             const unsigned short* __restrict__ wt,
                                             float* __restrict__ gi0) {
    int mt = blockIdx.x;             // 512 m-tiles of 64 rows
    int nt = blockIdx.y;             // 48 n-tiles of 64 cols
    int tid = threadIdx.x, wave = tid >> 6, lane = tid & 63;
    int mq = wave & 3, npair = wave >> 2;
    int arow = lane & 15, klq = (lane >> 4) * 8;
    const unsigned short* wHi = wt;  // Wi0 hi
    const unsigned short* wLo = wt + G3I;
    size_t abase = ((size_t)(mt * 64 + mq * 16 + arow)) * I_;
    int c0 = nt * 64 + npair * 32 + (lane & 15);
    floatx4 acc[2] = {};
    for (int it = 0; it < 32; ++it) {
        int kk = it * 32 + klq;
        float4 f0 = *(const float4*)(xf + abase + kk);
        float4 f1 = *(const float4*)(xf + abase + kk + 4);
        short8 ah, al;
        {
            float v0 = f0.x, v1 = f0.y, v2 = f0.z, v3 = f0.w;
            float v4 = f1.x, v5 = f1.y, v6 = f1.z, v7 = f1.w;
            unsigned short hb;
            hb = f2bf_rne(v0); ah[0] = (short)hb; al[0] = (short)f2bf_rne(v0 - bf2f(hb));
            hb = f2bf_rne(v1); ah[1] = (short)hb; al[1] = (short)f2bf_rne(v1 - bf2f(hb));
            hb = f2bf_rne(v2); ah[2] = (short)hb; al[2] = (short)f2bf_rne(v2 - bf2f(hb));
            hb = f2bf_rne(v3); ah[3] = (short)hb; al[3] = (short)f2bf_rne(v3 - bf2f(hb));
            hb = f2bf_rne(v4); ah[4] = (short)hb; al[4] = (short)f2bf_rne(v4 - bf2f(hb));
            hb = f2bf_rne(v5); ah[5] = (short)hb; al[5] = (short)f2bf_rne(v5 - bf2f(hb));
            hb = f2bf_rne(v6); ah[6] = (short)hb; al[6] = (short)f2bf_rne(v6 - bf2f(hb));
            hb = f2bf_rne(v7); ah[7] = (short)hb; al[7] = (short)f2bf_rne(v7 - bf2f(hb));
        }
#pragma unroll
        for (int n = 0; n < 2; ++n) {
            size_t bo = (size_t)(c0 + n * 16) * I_ + kk;
            short8 bh_ = *(const short8*)(wHi + bo);
            short8 bl_ = *(const short8*)(wLo + bo);
            acc[n] = __builtin_amdgcn_mfma_f32_16x16x32_bf16(ah, bh_, acc[n], 0, 0, 0);
            acc[n] = __builtin_amdgcn_mfma_f32_16x16x32_bf16(ah, bl_, acc[n], 0, 0, 0);
            acc[n] = __builtin_amdgcn_mfma_f32_16x16x32_bf16(al, bh_, acc[n], 0, 0, 0);
        }
    }
#pragma unroll
    for (int n = 0; n < 2; ++n)
#pragma unroll
        for (int r = 0; r < 4; ++r) {
            int rr = mt * 64 + mq * 16 + (lane >> 4) * 4 + r;
            int b = rr >> 10, t = rr & 1023;
            gi0[((size_t)t * B_ + b) * G3_ + c0 + n * 16] = acc[n][r];
        }
}

// ---- persistent GRU kernel (fence-free) ------------------------------------
// 256 blocks x 512 thr, 1 block/CU. Block grp owns units [grp*4, grp*4+4).
// Weights (Wh0,Wi1,Wh1 hi/lo, 9 real cols) live in LDS all sequence (144KB).
// Cross-block state transport: agent-scope relaxed atomics (sc0sc1 — write
// through to / read from the coherence point). NO __threadfence anywhere in
// the loop; barrier = vmcnt drain + monotonic counter + relaxed spin.
__global__ __launch_bounds__(512) void k_gru_pers(
    const unsigned short* __restrict__ wt,
    const float* __restrict__ gi0,
    const float* __restrict__ b_i, const float* __restrict__ b_h,
    unsigned short* __restrict__ hst,
    unsigned int* __restrict__ bar,
    float* __restrict__ out) {

    __shared__ unsigned short wlds[73728];  // 72 entries x 1024 shorts = 144KB
    __shared__ float red[3 * 32 * 17];      // stride-17 pad: 2 lanes/bank (free)

    const int grp = blockIdx.x;
    const int tid = threadIdx.x, wave = tid >> 6, lane = tid & 63;

    // ---- stage weight slice into LDS (once) --------------------------------
    for (int idx = tid; idx < 72 * 128; idx += 512) {
        int e = idx >> 7, chunk = idx & 127;
        int mp = e / 12, cle = e % 12;
        int m = mp >> 1, p = mp & 1;
        size_t gcol = (size_t)((cle >> 2) * H_ + grp * 4 + (cle & 3));
        const unsigned short* src = wt + (size_t)(m + 1) * 2 * G3I + (size_t)p * G3I
                                       + gcol * I_ + (size_t)chunk * 8;
        short8 v = *(const short8*)src;
        int byteoff = (e * 2048 + chunk * 16) ^ ((cle & 7) << 4);
        *(short8*)((char*)wlds + byteoff) = v;
    }

    // per-lane MFMA constants
    const int arow = lane & 15;
    const int c = lane & 15;
    const int cl = (c < 12) ? c : c - 4;      // lanes 12-15 duplicate n-gate
    const int xm = (cl & 7) << 4;
    int wb[6];
#pragma unroll
    for (int mp = 0; mp < 6; ++mp) wb[mp] = (mp * 12 + cl) * 2048;

    // act mapping: wave0 lanes 0-31 -> layer0 (b=lane, 4 units);
    //              wave1 lanes 0-31 -> layer1 (b=lane, 4 units)
    const bool act0 = (wave == 0) && (lane < 32);
    const bool act1 = (wave == 1) && (lane < 32);
    const int bact = lane;
    const int u0 = grp * 4;
    float4 biR = {}, biZ = {}, biN = {}, bhR = {}, bhZ = {}, bhN = {};
    if (act0 || act1) {
        int ly = act1 ? 1 : 0;
        const float* bi = b_i + (size_t)ly * G3_;
        const float* bh = b_h + (size_t)ly * G3_;
        biR = *(const float4*)(bi + u0);
        biZ = *(const float4*)(bi + H_ + u0);
        biN = *(const float4*)(bi + 2 * H_ + u0);
        bhR = *(const float4*)(bh + u0);
        bhZ = *(const float4*)(bh + H_ + u0);
        bhN = *(const float4*)(bh + 2 * H_ + u0);
    }
    float hp0 = 0.f, hp1 = 0.f, hp2 = 0.f, hp3 = 0.f;  // f32 h_prev (4 units)

    __syncthreads();

    for (int s = 0; s <= L_; ++s) {
        // gi0 prefetch for layer0 act (hides under MFMA phase)
        float4 g0r = {}, g0z = {}, g0n = {};
        if (act0 && s < L_) {
            const float* gsrc = gi0 + ((size_t)s * B_ + bact) * G3_;
            g0r = *(const float4*)(gsrc + u0);
            g0z = *(const float4*)(gsrc + H_ + u0);
            g0n = *(const float4*)(gsrc + 2 * H_ + u0);
        }

        // zero reduction buffer
        for (int i = tid; i < 3 * 32 * 17; i += 512) red[i] = 0.f;
        __syncthreads();

        const int rd0 = (s - 1) & 1;     // slot of h0[s-1]
        const int rd1 = s & 1;           // slot of h1[s-2]
        const unsigned short* a0h = hst + (size_t)(0 + rd0) * 32768;
        const unsigned short* a0l = hst + (size_t)(2 + rd0) * 32768;
        const unsigned short* a1h = hst + (size_t)(4 + rd1) * 32768;
        const unsigned short* a1l = hst + (size_t)(6 + rd1) * 32768;
        const char* wbase = (const char*)wlds;

        floatx4 acc[3][2] = {};
#pragma unroll
        for (int ks = 0; ks < 4; ++ks) {
            const int kk = wave * 128 + (lane >> 4) * 8 + ks * 32;  // shorts
            const int kb = kk * 2;                                   // bytes
            short8 p0h = ld16_agent(a0h + (size_t)arow * I_ + kk);
            short8 p0l = ld16_agent(a0l + (size_t)arow * I_ + kk);
            short8 p1h = ld16_agent(a0h + (size_t)(16 + arow) * I_ + kk);
            short8 p1l = ld16_agent(a0l + (size_t)(16 + arow) * I_ + kk);
            short8 q0h = ld16_agent(a1h + (size_t)arow * I_ + kk);
            short8 q0l = ld16_agent(a1l + (size_t)arow * I_ + kk);
            short8 q1h = ld16_agent(a1h + (size_t)(16 + arow) * I_ + kk);
            short8 q1l = ld16_agent(a1l + (size_t)(16 + arow) * I_ + kk);
            short8 u1h = *(const short8*)(wbase + ((wb[0] + kb) ^ xm));
            short8 u1l = *(const short8*)(wbase + ((wb[1] + kb) ^ xm));
            short8 u2h = *(const short8*)(wbase + ((wb[2] + kb) ^ xm));
            short8 u2l = *(const short8*)(wbase + ((wb[3] + kb) ^ xm));
            short8 u3h = *(const short8*)(wbase + ((wb[4] + kb) ^ xm));
            short8 u3l = *(const short8*)(wbase + ((wb[5] + kb) ^ xm));
            acc[0][0] = __builtin_amdgcn_mfma_f32_16x16x32_bf16(p0h, u1h, acc[0][0], 0, 0, 0);
            acc[0][0] = __builtin_amdgcn_mfma_f32_16x16x32_bf16(p0h, u1l, acc[0][0], 0, 0, 0);
            acc[0][0] = __builtin_amdgcn_mfma_f32_16x16x32_bf16(p0l, u1h, acc[0][0], 0, 0, 0);
            acc[0][1] = __builtin_amdgcn_mfma_f32_16x16x32_bf16(p1h, u1h, acc[0][1], 0, 0, 0);
            acc[0][1] = __builtin_amdgcn_mfma_f32_16x16x32_bf16(p1h, u1l, acc[0][1], 0, 0, 0);
            acc[0][1] = __builtin_amdgcn_mfma_f32_16x16x32_bf16(p1l, u1h, acc[0][1], 0, 0, 0);
            acc[1][0] = __builtin_amdgcn_mfma_f32_16x16x32_bf16(p0h, u2h, acc[1][0], 0, 0, 0);
            acc[1][0] = __builtin_amdgcn_mfma_f32_16x16x32_bf16(p0h, u2l, acc[1][0], 0, 0, 0);
            acc[1][0] = __builtin_amdgcn_mfma_f32_16x16x32_bf16(p0l, u2h, acc[1][0], 0, 0, 0);
            acc[1][1] = __builtin_amdgcn_mfma_f32_16x16x32_bf16(p1h, u2h, acc[1][1], 0, 0, 0);
            acc[1][1] = __builtin_amdgcn_mfma_f32_16x16x32_bf16(p1h, u2l, acc[1][1], 0, 0, 0);
            acc[1][1] = __builtin_amdgcn_mfma_f32_16x16x32_bf16(p1l, u2h, acc[1][1], 0, 0, 0);
            acc[2][0] = __builtin_amdgcn_mfma_f32_16x16x32_bf16(q0h, u3h, acc[2][0], 0, 0, 0);
            acc[2][0] = __builtin_amdgcn_mfma_f32_16x16x32_bf16(q0h, u3l, acc[2][0], 0, 0, 0);
            acc[2][0] = __builtin_amdgcn_mfma_f32_16x16x32_bf16(q0l, u3h, acc[2][0], 0, 0, 0);
            acc[2][1] = __builtin_amdgcn_mfma_f32_16x16x32_bf16(q1h, u3h, acc[2][1], 0, 0, 0);
            acc[2][1] = __builtin_amdgcn_mfma_f32_16x16x32_bf16(q1h, u3l, acc[2][1], 0, 0, 0);
            acc[2][1] = __builtin_amdgcn_mfma_f32_16x16x32_bf16(q1l, u3h, acc[2][1], 0, 0, 0);
        }

        // cross-wave reduce via LDS atomics (stride-17 rows: conflict-free)
#pragma unroll
        for (int m = 0; m < 3; ++m)
#pragma unroll
            for (int mm = 0; mm < 2; ++mm)
#pragma unroll
                for (int r = 0; r < 4; ++r) {
                    int row = mm * 16 + (lane >> 4) * 4 + r;
                    atomicAdd(&red[(m * 32 + row) * 17 + c], acc[m][mm][r]);
                }
        __syncthreads();

        // ---- epilogue -------------------------------------------------------
        if (act0 && s < L_) {
            const float* rr = &red[(0 * 32 + bact) * 17];
            float hn_[4];
#pragma unroll
            for (int j = 0; j < 4; ++j) {
                float gi_r = (&g0r.x)[j], gi_z = (&g0z.x)[j], gi_n = (&g0n.x)[j];
                float vr = gi_r + (&biR.x)[j] + rr[j] + (&bhR.x)[j];
                float vz = gi_z + (&biZ.x)[j] + rr[4 + j] + (&bhZ.x)[j];
                float r_ = 1.f / (1.f + __expf(-vr));
                float z_ = 1.f / (1.f + __expf(-vz));
                float ht = tanhf(gi_n + (&biN.x)[j] + r_ * (rr[8 + j] + (&bhN.x)[j]));
                float hpv = (j == 0) ? hp0 : (j == 1) ? hp1 : (j == 2) ? hp2 : hp3;
                hn_[j] = z_ * hpv + (1.f - z_) * ht;
            }
            hp0 = hn_[0]; hp1 = hn_[1]; hp2 = hn_[2]; hp3 = hn_[3];
            unsigned long long hip_ = 0, lop_ = 0;
#pragma unroll
            for (int j = 0; j < 4; ++j) {
                unsigned short hb16 = f2bf_rne(hn_[j]);
                hip_ |= (unsigned long long)hb16 << (16 * j);
                lop_ |= (unsigned long long)f2bf_rne(hn_[j] - bf2f(hb16)) << (16 * j);
            }
            int wr_ = s & 1;
            __hip_atomic_store((unsigned long long*)(hst + (size_t)(0 + wr_) * 32768 + bact * H_ + u0),
                               hip_, __ATOMIC_RELAXED, __HIP_MEMORY_SCOPE_AGENT);
            __hip_atomic_store((unsigned long long*)(hst + (size_t)(2 + wr_) * 32768 + bact * H_ + u0),
                               lop_, __ATOMIC_RELAXED, __HIP_MEMORY_SCOPE_AGENT);
            if (s == L_ - 1)
                *(float4*)(out + (size_t)B_ * L_ * H_ + bact * H_ + u0) =
                    make_float4(hn_[0], hn_[1], hn_[2], hn_[3]);
        }
        if (act1 && s >= 1) {
            int t = s - 1;
            const float* gg = &red[(1 * 32 + bact) * 17];
            const float* hh = &red[(2 * 32 + bact) * 17];
            float hn_[4];
#pragma unroll
            for (int j = 0; j < 4; ++j) {
                float vr = gg[j] + (&biR.x)[j] + hh[j] + (&bhR.x)[j];
                float vz = gg[4 + j] + (&biZ.x)[j] + hh[4 + j] + (&bhZ.x)[j];
                float r_ = 1.f / (1.f + __expf(-vr));
                float z_ = 1.f / (1.f + __expf(-vz));
                float ht = tanhf(gg[8 + j] + (&biN.x)[j] + r_ * (hh[8 + j] + (&bhN.x)[j]));
                float hpv = (j == 0) ? hp0 : (j == 1) ? hp1 : (j == 2) ? hp2 : hp3;
                hn_[j] = z_ * hpv + (1.f - z_) * ht;
            }
            hp0 = hn_[0]; hp1 = hn_[1]; hp2 = hn_[2]; hp3 = hn_[3];
            unsigned long long hip_ = 0, lop_ = 0;
#pragma unroll
            for (int j = 0; j < 4; ++j) {
                unsigned short hb16 = f2bf_rne(hn_[j]);
                hip_ |= (unsigned long long)hb16 << (16 * j);
                lop_ |= (unsigned long long)f2bf_rne(hn_[j] - bf2f(hb16)) << (16 * j);
            }
            int wr1 = (s - 1) & 1;
            __hip_atomic_store((unsigned long long*)(hst + (size_t)(4 + wr1) * 32768 + bact * H_ + u0),
                               hip_, __ATOMIC_RELAXED, __HIP_MEMORY_SCOPE_AGENT);
            __hip_atomic_store((unsigned long long*)(hst + (size_t)(6 + wr1) * 32768 + bact * H_ + u0),
                               lop_, __ATOMIC_RELAXED, __HIP_MEMORY_SCOPE_AGENT);
            *(float4*)(out + ((size_t)bact * L_ + t) * H_ + u0) =
                make_float4(hn_[0], hn_[1], hn_[2], hn_[3]);
            if (t == L_ - 1)
                *(float4*)(out + (size_t)B_ * L_ * H_ + (size_t)B_ * H_ + bact * H_ + u0) =
                    make_float4(hn_[0], hn_[1], hn_[2], hn_[3]);
        }

        // ---- fence-free grid barrier ---------------------------------------
        if (s < L_) {
            // drain this wave's write-through stores to the coherence point
            asm volatile("s_waitcnt vmcnt(0)" ::: "memory");
            __syncthreads();
            if (tid == 0) {
                __hip_atomic_fetch_add(bar, 1u, __ATOMIC_RELAXED, __HIP_MEMORY_SCOPE_AGENT);
                unsigned tgt = (unsigned)(s + 1) * NBLK;
                while (__hip_atomic_load(bar, __ATOMIC_RELAXED, __HIP_MEMORY_SCOPE_AGENT) < tgt)
                    __builtin_amdgcn_s_sleep(2);
            }
            __syncthreads();
        }
    }
}

extern "C" void kernel_launch(void* const* d_in, const int* in_sizes, int n_in,
                              void* d_out, int out_size, void* d_ws, size_t ws_size,
                              hipStream_t stream) {
    const float* x  = (const float*)d_in[0];
    const float* Wi = (const float*)d_in[1];
    const float* bi = (const float*)d_in[2];
    const float* Wh = (const float*)d_in[3];
    const float* bh = (const float*)d_in[4];
    float* out = (float*)d_out;
    char* ws = (char*)d_ws;

    // ws layout (bytes):
    //  [0, 48MB)              wt: 4 mats x {hi,lo} x [3072][1024] bf16
    //  [50331648, +512KB)     hst: 4 bufs x 2 slots x 32768 bf16
    //  [50855936, +4KB)       bar: grid barrier counter
    //  [51380224, +384MB)     gi0: f32 [L][B][3H]
    unsigned short* wt  = (unsigned short*)(ws);
    unsigned short* hst = (unsigned short*)(ws + 50331648);
    unsigned int*   bar = (unsigned int*)(ws + 50855936);
    float*          gi0 = (float*)(ws + 51380224);

    hipMemsetAsync(ws + 50331648, 0, 1048576, stream);
    k_trans_w<<<dim3(768, 4), 256, 0, stream>>>(Wi, Wh, wt);
    k_gi0<<<dim3(512, 48), 512, 0, stream>>>(x, wt, gi0);

    void* args[] = {&wt, &gi0, &bi, &bh, &hst, &bar, &out};
    hipLaunchCooperativeKernel((void*)k_gru_pers, dim3(NBLK), dim3(512), args, 0, stream);
}

// Round 5
// 28614.969 us; speedup vs baseline: 3.9958x; 1.3863x over previous
//
#include <hip/hip_runtime.h>
#include <cstdint>
#include <cstddef>

#define B_ 32
#define L_ 1024
#define I_ 1024
#define H_ 1024
#define G3_ 3072
#define G3I ((size_t)G3_ * I_)
#define NBLK 256

typedef short short8 __attribute__((ext_vector_type(8)));
typedef float floatx4 __attribute__((ext_vector_type(4)));

__device__ __forceinline__ unsigned short f2bf_rne(float f) {
    unsigned u = __float_as_uint(f);
    unsigned r = (u + 0x7fffu + ((u >> 16) & 1u)) >> 16;
    return (unsigned short)r;
}
__device__ __forceinline__ float bf2f(unsigned short u) {
    return __uint_as_float(((unsigned)u) << 16);
}

// coherence-point 16B load (bypasses L1/L2; serviced by Infinity Cache).
// Lane-consecutive addresses in the tiled state layout -> fully coalesced.
__device__ __forceinline__ short8 ld16_sc(const unsigned short* p) {
    short8 r;
    asm volatile("global_load_dwordx4 %0, %1, off sc0 sc1"
                 : "=v"(r) : "v"(p) : "memory");
    return r;
}

#define VM_WAIT(N) do { \
    asm volatile("s_waitcnt vmcnt(" #N ")" ::: "memory"); \
    __builtin_amdgcn_sched_barrier(0); \
} while (0)

// ---- prep: transpose weights [K][3H] -> [col][K], split bf16 hi/lo ---------
__global__ __launch_bounds__(256) void k_trans_w(const float* __restrict__ Wi,
                                                 const float* __restrict__ Wh,
                                                 unsigned short* __restrict__ wt) {
    int mat = blockIdx.y;            // 0=Wi0 1=Wh0 2=Wi1 3=Wh1
    int layer = mat >> 1, ish = mat & 1;
    const float* src = (ish ? Wh : Wi) + (size_t)layer * I_ * G3_;
    unsigned short* dhi = wt + (size_t)mat * 2u * G3I;
    unsigned short* dlo = dhi + G3I;
    int kt = blockIdx.x & 15;        // 16 k-tiles of 64
    int ct = blockIdx.x >> 4;        // 48 col-tiles of 64
    __shared__ float tile[64][65];
    int tid = threadIdx.x;
    int c_in = tid & 63, kr = tid >> 6;
    for (int pass = 0; pass < 16; ++pass) {
        int k = kt * 64 + pass * 4 + kr;
        tile[pass * 4 + kr][c_in] = src[(size_t)k * G3_ + ct * 64 + c_in];
    }
    __syncthreads();
    int k_out = tid & 63, cr = tid >> 6;
    for (int pass = 0; pass < 16; ++pass) {
        int c = ct * 64 + pass * 4 + cr;
        float f = tile[k_out][pass * 4 + cr];
        unsigned short hb = f2bf_rne(f);
        size_t o = (size_t)c * I_ + kt * 64 + k_out;
        dhi[o] = hb;
        dlo[o] = f2bf_rne(f - bf2f(hb));
    }
}

// ---- precompute gi0 = x @ Wi0 for ALL timesteps (one big GEMM) -------------
__global__ __launch_bounds__(512) void k_gi0(const float* __restrict__ xf,
                                             const unsigned short* __restrict__ wt,
                                             float* __restrict__ gi0) {
    int mt = blockIdx.x;             // 512 m-tiles of 64 rows
    int nt = blockIdx.y;             // 48 n-tiles of 64 cols
    int tid = threadIdx.x, wave = tid >> 6, lane = tid & 63;
    int mq = wave & 3, npair = wave >> 2;
    int arow = lane & 15, klq = (lane >> 4) * 8;
    const unsigned short* wHi = wt;  // Wi0 hi
    const unsigned short* wLo = wt + G3I;
    size_t abase = ((size_t)(mt * 64 + mq * 16 + arow)) * I_;
    int c0 = nt * 64 + npair * 32 + (lane & 15);
    floatx4 acc[2] = {};
    for (int it = 0; it < 32; ++it) {
        int kk = it * 32 + klq;
        float4 f0 = *(const float4*)(xf + abase + kk);
        float4 f1 = *(const float4*)(xf + abase + kk + 4);
        short8 ah, al;
        {
            float v0 = f0.x, v1 = f0.y, v2 = f0.z, v3 = f0.w;
            float v4 = f1.x, v5 = f1.y, v6 = f1.z, v7 = f1.w;
            unsigned short hb;
            hb = f2bf_rne(v0); ah[0] = (short)hb; al[0] = (short)f2bf_rne(v0 - bf2f(hb));
            hb = f2bf_rne(v1); ah[1] = (short)hb; al[1] = (short)f2bf_rne(v1 - bf2f(hb));
            hb = f2bf_rne(v2); ah[2] = (short)hb; al[2] = (short)f2bf_rne(v2 - bf2f(hb));
            hb = f2bf_rne(v3); ah[3] = (short)hb; al[3] = (short)f2bf_rne(v3 - bf2f(hb));
            hb = f2bf_rne(v4); ah[4] = (short)hb; al[4] = (short)f2bf_rne(v4 - bf2f(hb));
            hb = f2bf_rne(v5); ah[5] = (short)hb; al[5] = (short)f2bf_rne(v5 - bf2f(hb));
            hb = f2bf_rne(v6); ah[6] = (short)hb; al[6] = (short)f2bf_rne(v6 - bf2f(hb));
            hb = f2bf_rne(v7); ah[7] = (short)hb; al[7] = (short)f2bf_rne(v7 - bf2f(hb));
        }
#pragma unroll
        for (int n = 0; n < 2; ++n) {
            size_t bo = (size_t)(c0 + n * 16) * I_ + kk;
            short8 bh_ = *(const short8*)(wHi + bo);
            short8 bl_ = *(const short8*)(wLo + bo);
            acc[n] = __builtin_amdgcn_mfma_f32_16x16x32_bf16(ah, bh_, acc[n], 0, 0, 0);
            acc[n] = __builtin_amdgcn_mfma_f32_16x16x32_bf16(ah, bl_, acc[n], 0, 0, 0);
            acc[n] = __builtin_amdgcn_mfma_f32_16x16x32_bf16(al, bh_, acc[n], 0, 0, 0);
        }
    }
#pragma unroll
    for (int n = 0; n < 2; ++n)
#pragma unroll
        for (int r = 0; r < 4; ++r) {
            int rr = mt * 64 + mq * 16 + (lane >> 4) * 4 + r;
            int b = rr >> 10, t = rr & 1023;
            gi0[((size_t)t * B_ + b) * G3_ + c0 + n * 16] = acc[n][r];
        }
}

// ---- persistent GRU kernel (fence-free, tiled coalesced state) -------------
// Tiled state layout (shorts): region (S*2+slot)*65536, sub-buffer
// q=(b>>4)*2+part (part 0=hi 1=lo) *16384, tile kt*512, 16B unit l*8 where
// l = ((k>>3)&3)*16 + (b&15), short (k&7). Consumer lane l of tile kt reads
// exactly bytes [l*16, l*16+16) -> fully coalesced sc-bypass dwordx4 loads.
__global__ __launch_bounds__(512, 2) void k_gru_pers(
    const unsigned short* __restrict__ wt,
    const float* __restrict__ gi0,
    const float* __restrict__ b_i, const float* __restrict__ b_h,
    unsigned short* __restrict__ hst,
    unsigned int* __restrict__ bar,
    float* __restrict__ out) {

    __shared__ unsigned short wlds[73728];  // 72 entries x 1024 shorts = 144KB
    __shared__ float red[3 * 32 * 20];      // stride-20: 2-way banks (free)

    const int grp = blockIdx.x;
    const int tid = threadIdx.x, wave = tid >> 6, lane = tid & 63;

    // ---- stage weight slice into LDS (once) --------------------------------
    for (int idx = tid; idx < 72 * 128; idx += 512) {
        int e = idx >> 7, chunk = idx & 127;
        int mp = e / 12, cle = e % 12;
        int m = mp >> 1, p = mp & 1;
        size_t gcol = (size_t)((cle >> 2) * H_ + grp * 4 + (cle & 3));
        const unsigned short* src = wt + (size_t)(m + 1) * 2 * G3I + (size_t)p * G3I
                                       + gcol * I_ + (size_t)chunk * 8;
        short8 v = *(const short8*)src;
        int byteoff = (e * 2048 + chunk * 16) ^ ((cle & 7) << 4);
        *(short8*)((char*)wlds + byteoff) = v;
    }

    const int c = lane & 15;
    const int cl = (c < 12) ? c : c - 4;      // lanes 12-15 duplicate n-gate
    const int xm = (cl & 7) << 4;
    int wb[6];
#pragma unroll
    for (int mp = 0; mp < 6; ++mp) wb[mp] = (mp * 12 + cl) * 2048;
    const char* wbase = (const char*)wlds;

    const int woff = wave * 2048 + lane * 8;  // short offset of (kt=wave*4, l=lane)
    // producer constants (act lanes: waves 0/1, lane<32, b=lane)
    const int prodoff = (grp >> 3) * 512 + (((grp >> 1) & 3) * 16 + (lane & 15)) * 8
                      + (grp & 1) * 4;
    const int hq = (lane >> 4) * 2;           // batch-half sub-buffer pair
    const int u0 = grp * 4;
    float hp0 = 0.f, hp1 = 0.f, hp2 = 0.f, hp3 = 0.f;

    for (int i = tid; i < 3 * 32 * 20; i += 512) red[i] = 0.f;
    __syncthreads();

#define ISSUE(ks) do { \
    const int off_ = woff + (ks) * 512; \
    st[ks][0] = ld16_sc(A0 + off_); \
    st[ks][1] = ld16_sc(A0 + 16384 + off_); \
    st[ks][2] = ld16_sc(A0 + 32768 + off_); \
    st[ks][3] = ld16_sc(A0 + 49152 + off_); \
    st[ks][4] = ld16_sc(A1 + off_); \
    st[ks][5] = ld16_sc(A1 + 16384 + off_); \
    st[ks][6] = ld16_sc(A1 + 32768 + off_); \
    st[ks][7] = ld16_sc(A1 + 49152 + off_); \
} while (0)

#define MFMA_GRP(ks) do { \
    const int kb_ = wave * 256 + (lane >> 4) * 16 + (ks) * 64; \
    short8 u1h = *(const short8*)(wbase + ((wb[0] + kb_) ^ xm)); \
    short8 u1l = *(const short8*)(wbase + ((wb[1] + kb_) ^ xm)); \
    short8 u2h = *(const short8*)(wbase + ((wb[2] + kb_) ^ xm)); \
    short8 u2l = *(const short8*)(wbase + ((wb[3] + kb_) ^ xm)); \
    short8 u3h = *(const short8*)(wbase + ((wb[4] + kb_) ^ xm)); \
    short8 u3l = *(const short8*)(wbase + ((wb[5] + kb_) ^ xm)); \
    acc[0][0] = __builtin_amdgcn_mfma_f32_16x16x32_bf16(st[ks][0], u1h, acc[0][0], 0, 0, 0); \
    acc[0][0] = __builtin_amdgcn_mfma_f32_16x16x32_bf16(st[ks][0], u1l, acc[0][0], 0, 0, 0); \
    acc[0][0] = __builtin_amdgcn_mfma_f32_16x16x32_bf16(st[ks][1], u1h, acc[0][0], 0, 0, 0); \
    acc[0][1] = __builtin_amdgcn_mfma_f32_16x16x32_bf16(st[ks][2], u1h, acc[0][1], 0, 0, 0); \
    acc[0][1] = __builtin_amdgcn_mfma_f32_16x16x32_bf16(st[ks][2], u1l, acc[0][1], 0, 0, 0); \
    acc[0][1] = __builtin_amdgcn_mfma_f32_16x16x32_bf16(st[ks][3], u1h, acc[0][1], 0, 0, 0); \
    acc[1][0] = __builtin_amdgcn_mfma_f32_16x16x32_bf16(st[ks][0], u2h, acc[1][0], 0, 0, 0); \
    acc[1][0] = __builtin_amdgcn_mfma_f32_16x16x32_bf16(st[ks][0], u2l, acc[1][0], 0, 0, 0); \
    acc[1][0] = __builtin_amdgcn_mfma_f32_16x16x32_bf16(st[ks][1], u2h, acc[1][0], 0, 0, 0); \
    acc[1][1] = __builtin_amdgcn_mfma_f32_16x16x32_bf16(st[ks][2], u2h, acc[1][1], 0, 0, 0); \
    acc[1][1] = __builtin_amdgcn_mfma_f32_16x16x32_bf16(st[ks][2], u2l, acc[1][1], 0, 0, 0); \
    acc[1][1] = __builtin_amdgcn_mfma_f32_16x16x32_bf16(st[ks][3], u2h, acc[1][1], 0, 0, 0); \
    acc[2][0] = __builtin_amdgcn_mfma_f32_16x16x32_bf16(st[ks][4], u3h, acc[2][0], 0, 0, 0); \
    acc[2][0] = __builtin_amdgcn_mfma_f32_16x16x32_bf16(st[ks][4], u3l, acc[2][0], 0, 0, 0); \
    acc[2][0] = __builtin_amdgcn_mfma_f32_16x16x32_bf16(st[ks][5], u3h, acc[2][0], 0, 0, 0); \
    acc[2][1] = __builtin_amdgcn_mfma_f32_16x16x32_bf16(st[ks][6], u3h, acc[2][1], 0, 0, 0); \
    acc[2][1] = __builtin_amdgcn_mfma_f32_16x16x32_bf16(st[ks][6], u3l, acc[2][1], 0, 0, 0); \
    acc[2][1] = __builtin_amdgcn_mfma_f32_16x16x32_bf16(st[ks][7], u3h, acc[2][1], 0, 0, 0); \
} while (0)

    for (int s = 0; s <= L_; ++s) {
        // gi0 prefetch (older vmem ops only strengthen the counted waits)
        float4 g0r = {}, g0z = {}, g0n = {};
        if (wave == 0 && lane < 32 && s < L_) {
            const float* gsrc = gi0 + ((size_t)s * B_ + lane) * G3_;
            g0r = *(const float4*)(gsrc + u0);
            g0z = *(const float4*)(gsrc + H_ + u0);
            g0n = *(const float4*)(gsrc + 2 * H_ + u0);
        }

        const unsigned short* A0 = hst + (size_t)((s - 1) & 1) * 65536;
        const unsigned short* A1 = hst + (size_t)(2 + (s & 1)) * 65536;

        floatx4 acc[3][2] = {};
        short8 st[4][8];
        ISSUE(0); ISSUE(1);
        VM_WAIT(8);
        MFMA_GRP(0); ISSUE(2);
        VM_WAIT(8);
        MFMA_GRP(1); ISSUE(3);
        VM_WAIT(8);
        MFMA_GRP(2);
        VM_WAIT(0);
        MFMA_GRP(3);

        // cross-wave reduce (stride-20 rows: exact 2-way bank alias = free)
#pragma unroll
        for (int m = 0; m < 3; ++m)
#pragma unroll
            for (int mm = 0; mm < 2; ++mm)
#pragma unroll
                for (int r = 0; r < 4; ++r) {
                    int row = mm * 16 + (lane >> 4) * 4 + r;
                    atomicAdd(&red[(m * 32 + row) * 20 + c], acc[m][mm][r]);
                }
        __syncthreads();

        // ---- epilogue (act lanes) + reader-side red zeroing ----------------
        if (wave == 0 && lane < 32) {
            const int b = lane;
            float* r0 = &red[b * 20];
            if (s < L_) {
                const float4 biR = *(const float4*)(b_i + u0);
                const float4 biZ = *(const float4*)(b_i + H_ + u0);
                const float4 biN = *(const float4*)(b_i + 2 * H_ + u0);
                const float4 bhR = *(const float4*)(b_h + u0);
                const float4 bhZ = *(const float4*)(b_h + H_ + u0);
                const float4 bhN = *(const float4*)(b_h + 2 * H_ + u0);
                float hn_[4];
#pragma unroll
                for (int j = 0; j < 4; ++j) {
                    float vr = (&g0r.x)[j] + (&biR.x)[j] + r0[j] + (&bhR.x)[j];
                    float vz = (&g0z.x)[j] + (&biZ.x)[j] + r0[4 + j] + (&bhZ.x)[j];
                    float rg = 1.f / (1.f + __expf(-vr));
                    float zg = 1.f / (1.f + __expf(-vz));
                    float ht = tanhf((&g0n.x)[j] + (&biN.x)[j] + rg * (r0[8 + j] + (&bhN.x)[j]));
                    float hpv = (j == 0) ? hp0 : (j == 1) ? hp1 : (j == 2) ? hp2 : hp3;
                    hn_[j] = zg * hpv + (1.f - zg) * ht;
                }
                hp0 = hn_[0]; hp1 = hn_[1]; hp2 = hn_[2]; hp3 = hn_[3];
                unsigned long long hi_ = 0, lo_ = 0;
#pragma unroll
                for (int j = 0; j < 4; ++j) {
                    unsigned short hb16 = f2bf_rne(hn_[j]);
                    hi_ |= (unsigned long long)hb16 << (16 * j);
                    lo_ |= (unsigned long long)f2bf_rne(hn_[j] - bf2f(hb16)) << (16 * j);
                }
                const int wr_ = s & 1;
                unsigned short* dst = hst + (size_t)wr_ * 65536 + (size_t)hq * 16384 + prodoff;
                __hip_atomic_store((unsigned long long*)dst, hi_,
                                   __ATOMIC_RELAXED, __HIP_MEMORY_SCOPE_AGENT);
                __hip_atomic_store((unsigned long long*)(dst + 16384), lo_,
                                   __ATOMIC_RELAXED, __HIP_MEMORY_SCOPE_AGENT);
                if (s == L_ - 1)
                    *(float4*)(out + (size_t)B_ * L_ * H_ + b * H_ + u0) =
                        make_float4(hn_[0], hn_[1], hn_[2], hn_[3]);
            }
#pragma unroll
            for (int j = 0; j < 16; ++j) r0[j] = 0.f;
        } else if (wave == 1 && lane < 32) {
            const int b = lane;
            float* r1 = &red[(32 + b) * 20];
            float* r2 = &red[(64 + b) * 20];
            if (s >= 1) {
                const int t = s - 1;
                const float* bi1 = b_i + G3_;
                const float* bh1 = b_h + G3_;
                const float4 biR = *(const float4*)(bi1 + u0);
                const float4 biZ = *(const float4*)(bi1 + H_ + u0);
                const float4 biN = *(const float4*)(bi1 + 2 * H_ + u0);
                const float4 bhR = *(const float4*)(bh1 + u0);
                const float4 bhZ = *(const float4*)(bh1 + H_ + u0);
                const float4 bhN = *(const float4*)(bh1 + 2 * H_ + u0);
                float hn_[4];
#pragma unroll
                for (int j = 0; j < 4; ++j) {
                    float vr = r1[j] + (&biR.x)[j] + r2[j] + (&bhR.x)[j];
                    float vz = r1[4 + j] + (&biZ.x)[j] + r2[4 + j] + (&bhZ.x)[j];
                    float rg = 1.f / (1.f + __expf(-vr));
                    float zg = 1.f / (1.f + __expf(-vz));
                    float ht = tanhf(r1[8 + j] + (&biN.x)[j] + rg * (r2[8 + j] + (&bhN.x)[j]));
                    float hpv = (j == 0) ? hp0 : (j == 1) ? hp1 : (j == 2) ? hp2 : hp3;
                    hn_[j] = zg * hpv + (1.f - zg) * ht;
                }
                hp0 = hn_[0]; hp1 = hn_[1]; hp2 = hn_[2]; hp3 = hn_[3];
                unsigned long long hi_ = 0, lo_ = 0;
#pragma unroll
                for (int j = 0; j < 4; ++j) {
                    unsigned short hb16 = f2bf_rne(hn_[j]);
                    hi_ |= (unsigned long long)hb16 << (16 * j);
                    lo_ |= (unsigned long long)f2bf_rne(hn_[j] - bf2f(hb16)) << (16 * j);
                }
                const int wr1 = (s - 1) & 1;
                unsigned short* dst = hst + (size_t)(2 + wr1) * 65536 + (size_t)hq * 16384 + prodoff;
                __hip_atomic_store((unsigned long long*)dst, hi_,
                                   __ATOMIC_RELAXED, __HIP_MEMORY_SCOPE_AGENT);
                __hip_atomic_store((unsigned long long*)(dst + 16384), lo_,
                                   __ATOMIC_RELAXED, __HIP_MEMORY_SCOPE_AGENT);
                *(float4*)(out + ((size_t)b * L_ + t) * H_ + u0) =
                    make_float4(hn_[0], hn_[1], hn_[2], hn_[3]);
                if (t == L_ - 1)
                    *(float4*)(out + (size_t)B_ * L_ * H_ + (size_t)B_ * H_ + b * H_ + u0) =
                        make_float4(hn_[0], hn_[1], hn_[2], hn_[3]);
            }
#pragma unroll
            for (int j = 0; j < 16; ++j) { r1[j] = 0.f; r2[j] = 0.f; }
        }

        // ---- fence-free two-level grid barrier -----------------------------
        if (s < L_) {
            asm volatile("s_waitcnt vmcnt(0)" ::: "memory");
            __syncthreads();
            if (tid == 0) {
                const int g = grp >> 5;        // 8 groups of 32 blocks
                unsigned old = __hip_atomic_fetch_add(&bar[16 + g * 16], 1u,
                                   __ATOMIC_RELAXED, __HIP_MEMORY_SCOPE_AGENT);
                if (old == (unsigned)(s * 32 + 31))
                    __hip_atomic_fetch_add(&bar[0], 1u,
                                   __ATOMIC_RELAXED, __HIP_MEMORY_SCOPE_AGENT);
                const unsigned tgt = (unsigned)(s + 1) * 8u;
                while (__hip_atomic_load(&bar[0], __ATOMIC_RELAXED,
                                         __HIP_MEMORY_SCOPE_AGENT) < tgt)
                    __builtin_amdgcn_s_sleep(1);
            }
            __syncthreads();
        }
    }
#undef ISSUE
#undef MFMA_GRP
}

extern "C" void kernel_launch(void* const* d_in, const int* in_sizes, int n_in,
                              void* d_out, int out_size, void* d_ws, size_t ws_size,
                              hipStream_t stream) {
    const float* x  = (const float*)d_in[0];
    const float* Wi = (const float*)d_in[1];
    const float* bi = (const float*)d_in[2];
    const float* Wh = (const float*)d_in[3];
    const float* bh = (const float*)d_in[4];
    float* out = (float*)d_out;
    char* ws = (char*)d_ws;

    // ws layout (bytes):
    //  [0, 48MB)              wt: 4 mats x {hi,lo} x [3072][1024] bf16
    //  [50331648, +512KB)     hst: tiled state, 4 regions x 128KB
    //  [50855936, +4KB)       bar: barrier counters (root + 8 group, 64B apart)
    //  [51380224, +384MB)     gi0: f32 [L][B][3H]
    unsigned short* wt  = (unsigned short*)(ws);
    unsigned short* hst = (unsigned short*)(ws + 50331648);
    unsigned int*   bar = (unsigned int*)(ws + 50855936);
    float*          gi0 = (float*)(ws + 51380224);

    hipMemsetAsync(ws + 50331648, 0, 1048576, stream);
    k_trans_w<<<dim3(768, 4), 256, 0, stream>>>(Wi, Wh, wt);
    k_gi0<<<dim3(512, 48), 512, 0, stream>>>(x, wt, gi0);

    void* args[] = {&wt, &gi0, &bi, &bh, &hst, &bar, &out};
    hipLaunchCooperativeKernel((void*)k_gru_pers, dim3(NBLK), dim3(512), args, 0, stream);
}

// Round 8
// 26145.325 us; speedup vs baseline: 4.3733x; 1.0945x over previous
//
#include <hip/hip_runtime.h>
#include <cstdint>
#include <cstddef>

#define B_ 32
#define L_ 1024
#define I_ 1024
#define H_ 1024
#define G3_ 3072
#define G3I ((size_t)G3_ * I_)
#define NBLK 256

typedef short short8 __attribute__((ext_vector_type(8)));
typedef float floatx4 __attribute__((ext_vector_type(4)));

__device__ __forceinline__ unsigned short f2bf_rne(float f) {
    unsigned u = __float_as_uint(f);
    unsigned r = (u + 0x7fffu + ((u >> 16) & 1u)) >> 16;
    return (unsigned short)r;
}
__device__ __forceinline__ float bf2f(unsigned short u) {
    return __uint_as_float(((unsigned)u) << 16);
}

// coherence-point 16B load (bypasses L1/L2; serviced fresh by Infinity Cache).
// Lane-consecutive addresses in the tiled state layout -> fully coalesced.
// This is the PROVEN transport from the passing round-5 kernel.
__device__ __forceinline__ short8 ld16_sc(const unsigned short* p) {
    short8 r;
    asm volatile("global_load_dwordx4 %0, %1, off sc0 sc1"
                 : "=v"(r) : "v"(p) : "memory");
    return r;
}

#define VM_WAIT(N) do { \
    asm volatile("s_waitcnt vmcnt(" #N ")" ::: "memory"); \
    __builtin_amdgcn_sched_barrier(0); \
} while (0)

// ---- prep: transpose weights [K][3H] -> [col][K], split bf16 hi/lo ---------
__global__ __launch_bounds__(256) void k_trans_w(const float* __restrict__ Wi,
                                                 const float* __restrict__ Wh,
                                                 unsigned short* __restrict__ wt) {
    int mat = blockIdx.y;            // 0=Wi0 1=Wh0 2=Wi1 3=Wh1
    int layer = mat >> 1, ish = mat & 1;
    const float* src = (ish ? Wh : Wi) + (size_t)layer * I_ * G3_;
    unsigned short* dhi = wt + (size_t)mat * 2u * G3I;
    unsigned short* dlo = dhi + G3I;
    int kt = blockIdx.x & 15;        // 16 k-tiles of 64
    int ct = blockIdx.x >> 4;        // 48 col-tiles of 64
    __shared__ float tile[64][65];
    int tid = threadIdx.x;
    int c_in = tid & 63, kr = tid >> 6;
    for (int pass = 0; pass < 16; ++pass) {
        int k = kt * 64 + pass * 4 + kr;
        tile[pass * 4 + kr][c_in] = src[(size_t)k * G3_ + ct * 64 + c_in];
    }
    __syncthreads();
    int k_out = tid & 63, cr = tid >> 6;
    for (int pass = 0; pass < 16; ++pass) {
        int c = ct * 64 + pass * 4 + cr;
        float f = tile[k_out][pass * 4 + cr];
        unsigned short hb = f2bf_rne(f);
        size_t o = (size_t)c * I_ + kt * 64 + k_out;
        dhi[o] = hb;
        dlo[o] = f2bf_rne(f - bf2f(hb));
    }
}

// ---- precompute gi0 = x @ Wi0 for ALL timesteps (one big GEMM) -------------
__global__ __launch_bounds__(512) void k_gi0(const float* __restrict__ xf,
                                             const unsigned short* __restrict__ wt,
                                             float* __restrict__ gi0) {
    int mt = blockIdx.x;             // 512 m-tiles of 64 rows
    int nt = blockIdx.y;             // 48 n-tiles of 64 cols
    int tid = threadIdx.x, wave = tid >> 6, lane = tid & 63;
    int mq = wave & 3, npair = wave >> 2;
    int arow = lane & 15, klq = (lane >> 4) * 8;
    const unsigned short* wHi = wt;  // Wi0 hi
    const unsigned short* wLo = wt + G3I;
    size_t abase = ((size_t)(mt * 64 + mq * 16 + arow)) * I_;
    int c0 = nt * 64 + npair * 32 + (lane & 15);
    floatx4 acc[2] = {};
    for (int it = 0; it < 32; ++it) {
        int kk = it * 32 + klq;
        float4 f0 = *(const float4*)(xf + abase + kk);
        float4 f1 = *(const float4*)(xf + abase + kk + 4);
        short8 ah, al;
        {
            float v0 = f0.x, v1 = f0.y, v2 = f0.z, v3 = f0.w;
            float v4 = f1.x, v5 = f1.y, v6 = f1.z, v7 = f1.w;
            unsigned short hb;
            hb = f2bf_rne(v0); ah[0] = (short)hb; al[0] = (short)f2bf_rne(v0 - bf2f(hb));
            hb = f2bf_rne(v1); ah[1] = (short)hb; al[1] = (short)f2bf_rne(v1 - bf2f(hb));
            hb = f2bf_rne(v2); ah[2] = (short)hb; al[2] = (short)f2bf_rne(v2 - bf2f(hb));
            hb = f2bf_rne(v3); ah[3] = (short)hb; al[3] = (short)f2bf_rne(v3 - bf2f(hb));
            hb = f2bf_rne(v4); ah[4] = (short)hb; al[4] = (short)f2bf_rne(v4 - bf2f(hb));
            hb = f2bf_rne(v5); ah[5] = (short)hb; al[5] = (short)f2bf_rne(v5 - bf2f(hb));
            hb = f2bf_rne(v6); ah[6] = (short)hb; al[6] = (short)f2bf_rne(v6 - bf2f(hb));
            hb = f2bf_rne(v7); ah[7] = (short)hb; al[7] = (short)f2bf_rne(v7 - bf2f(hb));
        }
#pragma unroll
        for (int n = 0; n < 2; ++n) {
            size_t bo = (size_t)(c0 + n * 16) * I_ + kk;
            short8 bh_ = *(const short8*)(wHi + bo);
            short8 bl_ = *(const short8*)(wLo + bo);
            acc[n] = __builtin_amdgcn_mfma_f32_16x16x32_bf16(ah, bh_, acc[n], 0, 0, 0);
            acc[n] = __builtin_amdgcn_mfma_f32_16x16x32_bf16(ah, bl_, acc[n], 0, 0, 0);
            acc[n] = __builtin_amdgcn_mfma_f32_16x16x32_bf16(al, bh_, acc[n], 0, 0, 0);
        }
    }
#pragma unroll
    for (int n = 0; n < 2; ++n)
#pragma unroll
        for (int r = 0; r < 4; ++r) {
            int rr = mt * 64 + mq * 16 + (lane >> 4) * 4 + r;
            int b = rr >> 10, t = rr & 1023;
            gi0[((size_t)t * B_ + b) * G3_ + c0 + n * 16] = acc[n][r];
        }
}

// ---- persistent GRU kernel (round-5 transport, bf16-hi-only state) ---------
// State h is stored as plain bf16 (hi only); weights keep the hi/lo split.
// hst regions of 32768 shorts: 0,1 = h0 slot0/1 ; 2,3 = h1 slot0/1.
// Within a region: sub-buffer q=(b>>4) *16384 shorts, tile kt*512, 16B unit
// l*8 where l=((k>>3)&3)*16+(b&15), short (k&7). Consumer lane l of tile kt
// reads exactly bytes [l*16,l*16+16) -> fully coalesced sc dwordx4 loads.
__global__ __launch_bounds__(512, 2) void k_gru_pers(
    const unsigned short* __restrict__ wt,
    const float* __restrict__ gi0,
    const float* __restrict__ b_i, const float* __restrict__ b_h,
    unsigned short* __restrict__ hst,
    unsigned int* __restrict__ bar,
    float* __restrict__ out) {

    __shared__ unsigned short wlds[73728];  // 72 entries x 1024 shorts = 144KB
    __shared__ float red[3 * 32 * 20];      // stride-20: 2-way banks (free)

    const int grp = blockIdx.x;
    const int tid = threadIdx.x, wave = tid >> 6, lane = tid & 63;

    // ---- stage weight slice into LDS (once) --------------------------------
    for (int idx = tid; idx < 72 * 128; idx += 512) {
        int e = idx >> 7, chunk = idx & 127;
        int mp = e / 12, cle = e % 12;
        int m = mp >> 1, p = mp & 1;
        size_t gcol = (size_t)((cle >> 2) * H_ + grp * 4 + (cle & 3));
        const unsigned short* src = wt + (size_t)(m + 1) * 2 * G3I + (size_t)p * G3I
                                       + gcol * I_ + (size_t)chunk * 8;
        short8 v = *(const short8*)src;
        int byteoff = (e * 2048 + chunk * 16) ^ ((cle & 7) << 4);
        *(short8*)((char*)wlds + byteoff) = v;
    }

    const int c = lane & 15;
    const int cl = (c < 12) ? c : c - 4;      // lanes 12-15 duplicate n-gate
    const int xm = (cl & 7) << 4;
    int wb[6];
#pragma unroll
    for (int mp = 0; mp < 6; ++mp) wb[mp] = (mp * 12 + cl) * 2048;
    const char* wbase = (const char*)wlds;

    const int woff = wave * 2048 + lane * 8;  // short offset of (kt=wave*4, l=lane)
    const int prodoff = (grp >> 3) * 512 + (((grp >> 1) & 3) * 16 + (lane & 15)) * 8
                      + (grp & 1) * 4;
    const int u0 = grp * 4;
    float hp0 = 0.f, hp1 = 0.f, hp2 = 0.f, hp3 = 0.f;

    for (int i = tid; i < 3 * 32 * 20; i += 512) red[i] = 0.f;
    __syncthreads();

#define ISSUE(ks) do { \
    const int off_ = woff + (ks) * 512; \
    st[ks][0] = ld16_sc(A0 + off_); \
    st[ks][1] = ld16_sc(A0 + 16384 + off_); \
    st[ks][2] = ld16_sc(A1 + off_); \
    st[ks][3] = ld16_sc(A1 + 16384 + off_); \
} while (0)

#define MFMA_GRP(ks) do { \
    const int kb_ = wave * 256 + (lane >> 4) * 16 + (ks) * 64; \
    short8 u1h = *(const short8*)(wbase + ((wb[0] + kb_) ^ xm)); \
    short8 u1l = *(const short8*)(wbase + ((wb[1] + kb_) ^ xm)); \
    short8 u2h = *(const short8*)(wbase + ((wb[2] + kb_) ^ xm)); \
    short8 u2l = *(const short8*)(wbase + ((wb[3] + kb_) ^ xm)); \
    short8 u3h = *(const short8*)(wbase + ((wb[4] + kb_) ^ xm)); \
    short8 u3l = *(const short8*)(wbase + ((wb[5] + kb_) ^ xm)); \
    acc[0][0] = __builtin_amdgcn_mfma_f32_16x16x32_bf16(st[ks][0], u1h, acc[0][0], 0, 0, 0); \
    acc[0][0] = __builtin_amdgcn_mfma_f32_16x16x32_bf16(st[ks][0], u1l, acc[0][0], 0, 0, 0); \
    acc[0][1] = __builtin_amdgcn_mfma_f32_16x16x32_bf16(st[ks][1], u1h, acc[0][1], 0, 0, 0); \
    acc[0][1] = __builtin_amdgcn_mfma_f32_16x16x32_bf16(st[ks][1], u1l, acc[0][1], 0, 0, 0); \
    acc[1][0] = __builtin_amdgcn_mfma_f32_16x16x32_bf16(st[ks][0], u2h, acc[1][0], 0, 0, 0); \
    acc[1][0] = __builtin_amdgcn_mfma_f32_16x16x32_bf16(st[ks][0], u2l, acc[1][0], 0, 0, 0); \
    acc[1][1] = __builtin_amdgcn_mfma_f32_16x16x32_bf16(st[ks][1], u2h, acc[1][1], 0, 0, 0); \
    acc[1][1] = __builtin_amdgcn_mfma_f32_16x16x32_bf16(st[ks][1], u2l, acc[1][1], 0, 0, 0); \
    acc[2][0] = __builtin_amdgcn_mfma_f32_16x16x32_bf16(st[ks][2], u3h, acc[2][0], 0, 0, 0); \
    acc[2][0] = __builtin_amdgcn_mfma_f32_16x16x32_bf16(st[ks][2], u3l, acc[2][0], 0, 0, 0); \
    acc[2][1] = __builtin_amdgcn_mfma_f32_16x16x32_bf16(st[ks][3], u3h, acc[2][1], 0, 0, 0); \
    acc[2][1] = __builtin_amdgcn_mfma_f32_16x16x32_bf16(st[ks][3], u3l, acc[2][1], 0, 0, 0); \
} while (0)

    for (int s = 0; s <= L_; ++s) {
        // gi0 prefetch (normal cached loads; read-once data, harmless in L2)
        float4 g0r = {}, g0z = {}, g0n = {};
        if (wave == 0 && lane < 32 && s < L_) {
            const float* gsrc = gi0 + ((size_t)s * B_ + lane) * G3_;
            g0r = *(const float4*)(gsrc + u0);
            g0z = *(const float4*)(gsrc + H_ + u0);
            g0n = *(const float4*)(gsrc + 2 * H_ + u0);
        }

        const unsigned short* A0 = hst + (size_t)(0 + ((s - 1) & 1)) * 32768; // h0[s-1]
        const unsigned short* A1 = hst + (size_t)(2 + (s & 1)) * 32768;       // h1[s-2]

        floatx4 acc[3][2] = {};
        short8 st[4][4];
        ISSUE(0); ISSUE(1);
        VM_WAIT(4);
        MFMA_GRP(0); ISSUE(2);
        VM_WAIT(4);
        MFMA_GRP(1); ISSUE(3);
        VM_WAIT(4);
        MFMA_GRP(2);
        VM_WAIT(0);
        MFMA_GRP(3);

        // cross-wave reduce (stride-20 rows: exact 2-way bank alias = free)
#pragma unroll
        for (int m = 0; m < 3; ++m)
#pragma unroll
            for (int mm = 0; mm < 2; ++mm)
#pragma unroll
                for (int r = 0; r < 4; ++r) {
                    int row = mm * 16 + (lane >> 4) * 4 + r;
                    atomicAdd(&red[(m * 32 + row) * 20 + c], acc[m][mm][r]);
                }
        __syncthreads();

        // ---- epilogue (act lanes) + reader-side red zeroing ----------------
        if (wave == 0 && lane < 32) {
            const int b = lane;
            float* r0 = &red[b * 20];
            if (s < L_) {
                const float4 biR = *(const float4*)(b_i + u0);
                const float4 biZ = *(const float4*)(b_i + H_ + u0);
                const float4 biN = *(const float4*)(b_i + 2 * H_ + u0);
                const float4 bhR = *(const float4*)(b_h + u0);
                const float4 bhZ = *(const float4*)(b_h + H_ + u0);
                const float4 bhN = *(const float4*)(b_h + 2 * H_ + u0);
                float hn_[4];
#pragma unroll
                for (int j = 0; j < 4; ++j) {
                    float vr = (&g0r.x)[j] + (&biR.x)[j] + r0[j] + (&bhR.x)[j];
                    float vz = (&g0z.x)[j] + (&biZ.x)[j] + r0[4 + j] + (&bhZ.x)[j];
                    float rg = 1.f / (1.f + __expf(-vr));
                    float zg = 1.f / (1.f + __expf(-vz));
                    float ht = tanhf((&g0n.x)[j] + (&biN.x)[j] + rg * (r0[8 + j] + (&bhN.x)[j]));
                    float hpv = (j == 0) ? hp0 : (j == 1) ? hp1 : (j == 2) ? hp2 : hp3;
                    hn_[j] = zg * hpv + (1.f - zg) * ht;
                }
                hp0 = hn_[0]; hp1 = hn_[1]; hp2 = hn_[2]; hp3 = hn_[3];
                unsigned long long hi_ = 0;
#pragma unroll
                for (int j = 0; j < 4; ++j)
                    hi_ |= (unsigned long long)f2bf_rne(hn_[j]) << (16 * j);
                unsigned short* dst = hst + (size_t)(0 + (s & 1)) * 32768
                                    + (size_t)(b >> 4) * 16384 + prodoff;
                __hip_atomic_store((unsigned long long*)dst, hi_,
                                   __ATOMIC_RELAXED, __HIP_MEMORY_SCOPE_AGENT);
                if (s == L_ - 1)
                    *(float4*)(out + (size_t)B_ * L_ * H_ + b * H_ + u0) =
                        make_float4(hn_[0], hn_[1], hn_[2], hn_[3]);
            }
#pragma unroll
            for (int j = 0; j < 16; ++j) r0[j] = 0.f;
        } else if (wave == 1 && lane < 32) {
            const int b = lane;
            float* r1 = &red[(32 + b) * 20];
            float* r2 = &red[(64 + b) * 20];
            if (s >= 1) {
                const int t = s - 1;
                const float* bi1 = b_i + G3_;
                const float* bh1 = b_h + G3_;
                const float4 biR = *(const float4*)(bi1 + u0);
                const float4 biZ = *(const float4*)(bi1 + H_ + u0);
                const float4 biN = *(const float4*)(bi1 + 2 * H_ + u0);
                const float4 bhR = *(const float4*)(bh1 + u0);
                const float4 bhZ = *(const float4*)(bh1 + H_ + u0);
                const float4 bhN = *(const float4*)(bh1 + 2 * H_ + u0);
                float hn_[4];
#pragma unroll
                for (int j = 0; j < 4; ++j) {
                    float vr = r1[j] + (&biR.x)[j] + r2[j] + (&bhR.x)[j];
                    float vz = r1[4 + j] + (&biZ.x)[j] + r2[4 + j] + (&bhZ.x)[j];
                    float rg = 1.f / (1.f + __expf(-vr));
                    float zg = 1.f / (1.f + __expf(-vz));
                    float ht = tanhf(r1[8 + j] + (&biN.x)[j] + rg * (r2[8 + j] + (&bhN.x)[j]));
                    float hpv = (j == 0) ? hp0 : (j == 1) ? hp1 : (j == 2) ? hp2 : hp3;
                    hn_[j] = zg * hpv + (1.f - zg) * ht;
                }
                hp0 = hn_[0]; hp1 = hn_[1]; hp2 = hn_[2]; hp3 = hn_[3];
                unsigned long long hi_ = 0;
#pragma unroll
                for (int j = 0; j < 4; ++j)
                    hi_ |= (unsigned long long)f2bf_rne(hn_[j]) << (16 * j);
                unsigned short* dst = hst + (size_t)(2 + ((s - 1) & 1)) * 32768
                                    + (size_t)(b >> 4) * 16384 + prodoff;
                __hip_atomic_store((unsigned long long*)dst, hi_,
                                   __ATOMIC_RELAXED, __HIP_MEMORY_SCOPE_AGENT);
                *(float4*)(out + ((size_t)b * L_ + t) * H_ + u0) =
                    make_float4(hn_[0], hn_[1], hn_[2], hn_[3]);
                if (t == L_ - 1)
                    *(float4*)(out + (size_t)B_ * L_ * H_ + (size_t)B_ * H_ + b * H_ + u0) =
                        make_float4(hn_[0], hn_[1], hn_[2], hn_[3]);
            }
#pragma unroll
            for (int j = 0; j < 16; ++j) { r1[j] = 0.f; r2[j] = 0.f; }
        }

        // ---- grid barrier (round-5 pattern; arrivals spread 1KB apart) -----
        if (s < L_) {
            asm volatile("s_waitcnt vmcnt(0)" ::: "memory");
            __syncthreads();
            if (tid == 0) {
                const int g = grp >> 5;        // 8 groups of 32 blocks
                __hip_atomic_fetch_add(&bar[g * 256], 1u,
                                       __ATOMIC_RELAXED, __HIP_MEMORY_SCOPE_AGENT);
                if ((grp & 31) == 0) {
                    while (__hip_atomic_load(&bar[g * 256], __ATOMIC_RELAXED,
                                             __HIP_MEMORY_SCOPE_AGENT)
                           < (unsigned)(s + 1) * 32u)
                        __builtin_amdgcn_s_sleep(2);
                    __hip_atomic_fetch_add(&bar[4096], 1u,
                                           __ATOMIC_RELAXED, __HIP_MEMORY_SCOPE_AGENT);
                }
                while (__hip_atomic_load(&bar[4096], __ATOMIC_RELAXED,
                                         __HIP_MEMORY_SCOPE_AGENT)
                       < (unsigned)(s + 1) * 8u)
                    __builtin_amdgcn_s_sleep(2);
            }
            __syncthreads();
        }
    }
#undef ISSUE
#undef MFMA_GRP
}

extern "C" void kernel_launch(void* const* d_in, const int* in_sizes, int n_in,
                              void* d_out, int out_size, void* d_ws, size_t ws_size,
                              hipStream_t stream) {
    const float* x  = (const float*)d_in[0];
    const float* Wi = (const float*)d_in[1];
    const float* bi = (const float*)d_in[2];
    const float* Wh = (const float*)d_in[3];
    const float* bh = (const float*)d_in[4];
    float* out = (float*)d_out;
    char* ws = (char*)d_ws;

    // ws layout (bytes):
    //  [0, 48MB)              wt: 4 mats x {hi,lo} x [3072][1024] bf16
    //  [50331648, +256KB)     hst: 4 regions x 32768 bf16 (h0 s0/s1, h1 s0/s1)
    //  [50855936, +512KB)     bar: barrier counters (spread 1KB apart)
    //  [51380224, +384MB)     gi0: f32 [L][B][3H]
    unsigned short* wt  = (unsigned short*)(ws);
    unsigned short* hst = (unsigned short*)(ws + 50331648);
    unsigned int*   bar = (unsigned int*)(ws + 50855936);
    float*          gi0 = (float*)(ws + 51380224);

    hipMemsetAsync(ws + 50331648, 0, 1048576, stream);
    k_trans_w<<<dim3(768, 4), 256, 0, stream>>>(Wi, Wh, wt);
    k_gi0<<<dim3(512, 48), 512, 0, stream>>>(x, wt, gi0);

    void* args[] = {&wt, &gi0, &bi, &bh, &hst, &bar, &out};
    hipLaunchCooperativeKernel((void*)k_gru_pers, dim3(NBLK), dim3(512), args, 0, stream);
}

// Round 9
// 25907.220 us; speedup vs baseline: 4.4135x; 1.0092x over previous
//
#include <hip/hip_runtime.h>
#include <cstdint>
#include <cstddef>

#define B_ 32
#define L_ 1024
#define I_ 1024
#define H_ 1024
#define G3_ 3072
#define G3I ((size_t)G3_ * I_)
#define NBLK 256

typedef short short8 __attribute__((ext_vector_type(8)));
typedef float floatx4 __attribute__((ext_vector_type(4)));

__device__ __forceinline__ unsigned short f2bf_rne(float f) {
    unsigned u = __float_as_uint(f);
    unsigned r = (u + 0x7fffu + ((u >> 16) & 1u)) >> 16;
    return (unsigned short)r;
}
__device__ __forceinline__ float bf2f(unsigned short u) {
    return __uint_as_float(((unsigned)u) << 16);
}

// coherence-point 16B load (bypasses L1/L2; serviced fresh by Infinity Cache).
// Lane-consecutive addresses in the tiled state layout -> fully coalesced.
// PROVEN transport (rounds 5 and 8).
__device__ __forceinline__ short8 ld16_sc(const unsigned short* p) {
    short8 r;
    asm volatile("global_load_dwordx4 %0, %1, off sc0 sc1"
                 : "=v"(r) : "v"(p) : "memory");
    return r;
}

#define VM_WAIT(N) do { \
    asm volatile("s_waitcnt vmcnt(" #N ")" ::: "memory"); \
    __builtin_amdgcn_sched_barrier(0); \
} while (0)

// ---- prep: transpose weights [K][3H] -> [col][K], split bf16 hi/lo ---------
__global__ __launch_bounds__(256) void k_trans_w(const float* __restrict__ Wi,
                                                 const float* __restrict__ Wh,
                                                 unsigned short* __restrict__ wt) {
    int mat = blockIdx.y;            // 0=Wi0 1=Wh0 2=Wi1 3=Wh1
    int layer = mat >> 1, ish = mat & 1;
    const float* src = (ish ? Wh : Wi) + (size_t)layer * I_ * G3_;
    unsigned short* dhi = wt + (size_t)mat * 2u * G3I;
    unsigned short* dlo = dhi + G3I;
    int kt = blockIdx.x & 15;        // 16 k-tiles of 64
    int ct = blockIdx.x >> 4;        // 48 col-tiles of 64
    __shared__ float tile[64][65];
    int tid = threadIdx.x;
    int c_in = tid & 63, kr = tid >> 6;
    for (int pass = 0; pass < 16; ++pass) {
        int k = kt * 64 + pass * 4 + kr;
        tile[pass * 4 + kr][c_in] = src[(size_t)k * G3_ + ct * 64 + c_in];
    }
    __syncthreads();
    int k_out = tid & 63, cr = tid >> 6;
    for (int pass = 0; pass < 16; ++pass) {
        int c = ct * 64 + pass * 4 + cr;
        float f = tile[k_out][pass * 4 + cr];
        unsigned short hb = f2bf_rne(f);
        size_t o = (size_t)c * I_ + kt * 64 + k_out;
        dhi[o] = hb;
        dlo[o] = f2bf_rne(f - bf2f(hb));
    }
}

// ---- precompute gi0 = x @ Wi0 for ALL timesteps (one big GEMM) -------------
__global__ __launch_bounds__(512) void k_gi0(const float* __restrict__ xf,
                                             const unsigned short* __restrict__ wt,
                                             float* __restrict__ gi0) {
    int mt = blockIdx.x;             // 512 m-tiles of 64 rows
    int nt = blockIdx.y;             // 48 n-tiles of 64 cols
    int tid = threadIdx.x, wave = tid >> 6, lane = tid & 63;
    int mq = wave & 3, npair = wave >> 2;
    int arow = lane & 15, klq = (lane >> 4) * 8;
    const unsigned short* wHi = wt;  // Wi0 hi
    const unsigned short* wLo = wt + G3I;
    size_t abase = ((size_t)(mt * 64 + mq * 16 + arow)) * I_;
    int c0 = nt * 64 + npair * 32 + (lane & 15);
    floatx4 acc[2] = {};
    for (int it = 0; it < 32; ++it) {
        int kk = it * 32 + klq;
        float4 f0 = *(const float4*)(xf + abase + kk);
        float4 f1 = *(const float4*)(xf + abase + kk + 4);
        short8 ah, al;
        {
            float v0 = f0.x, v1 = f0.y, v2 = f0.z, v3 = f0.w;
            float v4 = f1.x, v5 = f1.y, v6 = f1.z, v7 = f1.w;
            unsigned short hb;
            hb = f2bf_rne(v0); ah[0] = (short)hb; al[0] = (short)f2bf_rne(v0 - bf2f(hb));
            hb = f2bf_rne(v1); ah[1] = (short)hb; al[1] = (short)f2bf_rne(v1 - bf2f(hb));
            hb = f2bf_rne(v2); ah[2] = (short)hb; al[2] = (short)f2bf_rne(v2 - bf2f(hb));
            hb = f2bf_rne(v3); ah[3] = (short)hb; al[3] = (short)f2bf_rne(v3 - bf2f(hb));
            hb = f2bf_rne(v4); ah[4] = (short)hb; al[4] = (short)f2bf_rne(v4 - bf2f(hb));
            hb = f2bf_rne(v5); ah[5] = (short)hb; al[5] = (short)f2bf_rne(v5 - bf2f(hb));
            hb = f2bf_rne(v6); ah[6] = (short)hb; al[6] = (short)f2bf_rne(v6 - bf2f(hb));
            hb = f2bf_rne(v7); ah[7] = (short)hb; al[7] = (short)f2bf_rne(v7 - bf2f(hb));
        }
#pragma unroll
        for (int n = 0; n < 2; ++n) {
            size_t bo = (size_t)(c0 + n * 16) * I_ + kk;
            short8 bh_ = *(const short8*)(wHi + bo);
            short8 bl_ = *(const short8*)(wLo + bo);
            acc[n] = __builtin_amdgcn_mfma_f32_16x16x32_bf16(ah, bh_, acc[n], 0, 0, 0);
            acc[n] = __builtin_amdgcn_mfma_f32_16x16x32_bf16(ah, bl_, acc[n], 0, 0, 0);
            acc[n] = __builtin_amdgcn_mfma_f32_16x16x32_bf16(al, bh_, acc[n], 0, 0, 0);
        }
    }
#pragma unroll
    for (int n = 0; n < 2; ++n)
#pragma unroll
        for (int r = 0; r < 4; ++r) {
            int rr = mt * 64 + mq * 16 + (lane >> 4) * 4 + r;
            int b = rr >> 10, t = rr & 1023;
            gi0[((size_t)t * B_ + b) * G3_ + c0 + n * 16] = acc[n][r];
        }
}

// ---- persistent GRU kernel (round-8 transport; deep load pipeline) ---------
// State h stored as plain bf16 (hi only); weights keep hi/lo split.
// hst regions of 32768 shorts: 0,1 = h0 slot0/1 ; 2,3 = h1 slot0/1.
// All 16 state sc-loads issue up-front (one IC latency exposure), gi0 loads
// after, then counted vmcnt(12/8/4/0) interleave with the 4 MFMA groups.
__global__ __launch_bounds__(512, 2) void k_gru_pers(
    const unsigned short* __restrict__ wt,
    const float* __restrict__ gi0,
    const float* __restrict__ b_i, const float* __restrict__ b_h,
    unsigned short* __restrict__ hst,
    unsigned int* __restrict__ bar,
    float* __restrict__ out) {

    __shared__ unsigned short wlds[73728];  // 72 entries x 1024 shorts = 144KB
    __shared__ float red[3 * 32 * 20];      // stride-20: 2-way banks (free)

    const int grp = blockIdx.x;
    const int tid = threadIdx.x, wave = tid >> 6, lane = tid & 63;

    // ---- stage weight slice into LDS (once) --------------------------------
    for (int idx = tid; idx < 72 * 128; idx += 512) {
        int e = idx >> 7, chunk = idx & 127;
        int mp = e / 12, cle = e % 12;
        int m = mp >> 1, p = mp & 1;
        size_t gcol = (size_t)((cle >> 2) * H_ + grp * 4 + (cle & 3));
        const unsigned short* src = wt + (size_t)(m + 1) * 2 * G3I + (size_t)p * G3I
                                       + gcol * I_ + (size_t)chunk * 8;
        short8 v = *(const short8*)src;
        int byteoff = (e * 2048 + chunk * 16) ^ ((cle & 7) << 4);
        *(short8*)((char*)wlds + byteoff) = v;
    }

    const int c = lane & 15;
    const int cl = (c < 12) ? c : c - 4;      // lanes 12-15 duplicate n-gate
    const int xm = (cl & 7) << 4;
    int wb[6];
#pragma unroll
    for (int mp = 0; mp < 6; ++mp) wb[mp] = (mp * 12 + cl) * 2048;
    const char* wbase = (const char*)wlds;

    const int woff = wave * 2048 + lane * 8;  // short offset of (kt=wave*4, l=lane)
    const int prodoff = (grp >> 3) * 512 + (((grp >> 1) & 3) * 16 + (lane & 15)) * 8
                      + (grp & 1) * 4;
    const int u0 = grp * 4;
    float hp0 = 0.f, hp1 = 0.f, hp2 = 0.f, hp3 = 0.f;

    // ---- hoist loop-invariant biases into registers (act lanes only) -------
    float4 biR = {}, biZ = {}, biN = {}, bhR = {}, bhZ = {}, bhN = {};
    if (wave == 0 && lane < 32) {
        biR = *(const float4*)(b_i + u0);
        biZ = *(const float4*)(b_i + H_ + u0);
        biN = *(const float4*)(b_i + 2 * H_ + u0);
        bhR = *(const float4*)(b_h + u0);
        bhZ = *(const float4*)(b_h + H_ + u0);
        bhN = *(const float4*)(b_h + 2 * H_ + u0);
    } else if (wave == 1 && lane < 32) {
        const float* bi1 = b_i + G3_;
        const float* bh1 = b_h + G3_;
        biR = *(const float4*)(bi1 + u0);
        biZ = *(const float4*)(bi1 + H_ + u0);
        biN = *(const float4*)(bi1 + 2 * H_ + u0);
        bhR = *(const float4*)(bh1 + u0);
        bhZ = *(const float4*)(bh1 + H_ + u0);
        bhN = *(const float4*)(bh1 + 2 * H_ + u0);
    }

    for (int i = tid; i < 3 * 32 * 20; i += 512) red[i] = 0.f;
    __syncthreads();

#define ISSUE(ks) do { \
    const int off_ = woff + (ks) * 512; \
    st[ks][0] = ld16_sc(A0 + off_); \
    st[ks][1] = ld16_sc(A0 + 16384 + off_); \
    st[ks][2] = ld16_sc(A1 + off_); \
    st[ks][3] = ld16_sc(A1 + 16384 + off_); \
} while (0)

#define MFMA_GRP(ks) do { \
    const int kb_ = wave * 256 + (lane >> 4) * 16 + (ks) * 64; \
    short8 u1h = *(const short8*)(wbase + ((wb[0] + kb_) ^ xm)); \
    short8 u1l = *(const short8*)(wbase + ((wb[1] + kb_) ^ xm)); \
    short8 u2h = *(const short8*)(wbase + ((wb[2] + kb_) ^ xm)); \
    short8 u2l = *(const short8*)(wbase + ((wb[3] + kb_) ^ xm)); \
    short8 u3h = *(const short8*)(wbase + ((wb[4] + kb_) ^ xm)); \
    short8 u3l = *(const short8*)(wbase + ((wb[5] + kb_) ^ xm)); \
    acc[0][0] = __builtin_amdgcn_mfma_f32_16x16x32_bf16(st[ks][0], u1h, acc[0][0], 0, 0, 0); \
    acc[0][0] = __builtin_amdgcn_mfma_f32_16x16x32_bf16(st[ks][0], u1l, acc[0][0], 0, 0, 0); \
    acc[0][1] = __builtin_amdgcn_mfma_f32_16x16x32_bf16(st[ks][1], u1h, acc[0][1], 0, 0, 0); \
    acc[0][1] = __builtin_amdgcn_mfma_f32_16x16x32_bf16(st[ks][1], u1l, acc[0][1], 0, 0, 0); \
    acc[1][0] = __builtin_amdgcn_mfma_f32_16x16x32_bf16(st[ks][0], u2h, acc[1][0], 0, 0, 0); \
    acc[1][0] = __builtin_amdgcn_mfma_f32_16x16x32_bf16(st[ks][0], u2l, acc[1][0], 0, 0, 0); \
    acc[1][1] = __builtin_amdgcn_mfma_f32_16x16x32_bf16(st[ks][1], u2h, acc[1][1], 0, 0, 0); \
    acc[1][1] = __builtin_amdgcn_mfma_f32_16x16x32_bf16(st[ks][1], u2l, acc[1][1], 0, 0, 0); \
    acc[2][0] = __builtin_amdgcn_mfma_f32_16x16x32_bf16(st[ks][2], u3h, acc[2][0], 0, 0, 0); \
    acc[2][0] = __builtin_amdgcn_mfma_f32_16x16x32_bf16(st[ks][2], u3l, acc[2][0], 0, 0, 0); \
    acc[2][1] = __builtin_amdgcn_mfma_f32_16x16x32_bf16(st[ks][3], u3h, acc[2][1], 0, 0, 0); \
    acc[2][1] = __builtin_amdgcn_mfma_f32_16x16x32_bf16(st[ks][3], u3l, acc[2][1], 0, 0, 0); \
} while (0)

    for (int s = 0; s <= L_; ++s) {
        const unsigned short* A0 = hst + (size_t)(0 + ((s - 1) & 1)) * 32768; // h0[s-1]
        const unsigned short* A1 = hst + (size_t)(2 + (s & 1)) * 32768;       // h1[s-2]

        floatx4 acc[3][2] = {};
        short8 st[4][4];
        // all 16 state loads up-front: single IC latency exposure
        ISSUE(0); ISSUE(1); ISSUE(2); ISSUE(3);

        // gi0 prefetch issued after state loads (completes by VM_WAIT(0))
        float4 g0r = {}, g0z = {}, g0n = {};
        if (wave == 0 && lane < 32 && s < L_) {
            const float* gsrc = gi0 + ((size_t)s * B_ + lane) * G3_;
            g0r = *(const float4*)(gsrc + u0);
            g0z = *(const float4*)(gsrc + H_ + u0);
            g0n = *(const float4*)(gsrc + 2 * H_ + u0);
        }

        VM_WAIT(12);   // st[0] complete (wave0: 19 outstanding -> 7 done >= 4)
        MFMA_GRP(0);
        VM_WAIT(8);    // st[1] complete
        MFMA_GRP(1);
        VM_WAIT(4);    // st[2] complete
        MFMA_GRP(2);
        VM_WAIT(0);    // st[3] + gi0 complete
        MFMA_GRP(3);

        // cross-wave reduce (stride-20 rows: exact 2-way bank alias = free)
#pragma unroll
        for (int m = 0; m < 3; ++m)
#pragma unroll
            for (int mm = 0; mm < 2; ++mm)
#pragma unroll
                for (int r = 0; r < 4; ++r) {
                    int row = mm * 16 + (lane >> 4) * 4 + r;
                    atomicAdd(&red[(m * 32 + row) * 20 + c], acc[m][mm][r]);
                }
        __syncthreads();

        // ---- epilogue (act lanes) + reader-side red zeroing ----------------
        if (wave == 0 && lane < 32) {
            const int b = lane;
            float* r0 = &red[b * 20];
            if (s < L_) {
                float hn_[4];
#pragma unroll
                for (int j = 0; j < 4; ++j) {
                    float vr = (&g0r.x)[j] + (&biR.x)[j] + r0[j] + (&bhR.x)[j];
                    float vz = (&g0z.x)[j] + (&biZ.x)[j] + r0[4 + j] + (&bhZ.x)[j];
                    float rg = 1.f / (1.f + __expf(-vr));
                    float zg = 1.f / (1.f + __expf(-vz));
                    float ht = tanhf((&g0n.x)[j] + (&biN.x)[j] + rg * (r0[8 + j] + (&bhN.x)[j]));
                    float hpv = (j == 0) ? hp0 : (j == 1) ? hp1 : (j == 2) ? hp2 : hp3;
                    hn_[j] = zg * hpv + (1.f - zg) * ht;
                }
                hp0 = hn_[0]; hp1 = hn_[1]; hp2 = hn_[2]; hp3 = hn_[3];
                unsigned long long hi_ = 0;
#pragma unroll
                for (int j = 0; j < 4; ++j)
                    hi_ |= (unsigned long long)f2bf_rne(hn_[j]) << (16 * j);
                unsigned short* dst = hst + (size_t)(0 + (s & 1)) * 32768
                                    + (size_t)(b >> 4) * 16384 + prodoff;
                __hip_atomic_store((unsigned long long*)dst, hi_,
                                   __ATOMIC_RELAXED, __HIP_MEMORY_SCOPE_AGENT);
                if (s == L_ - 1)
                    *(float4*)(out + (size_t)B_ * L_ * H_ + b * H_ + u0) =
                        make_float4(hn_[0], hn_[1], hn_[2], hn_[3]);
            }
#pragma unroll
            for (int j = 0; j < 16; ++j) r0[j] = 0.f;
        } else if (wave == 1 && lane < 32) {
            const int b = lane;
            float* r1 = &red[(32 + b) * 20];
            float* r2 = &red[(64 + b) * 20];
            if (s >= 1) {
                const int t = s - 1;
                float hn_[4];
#pragma unroll
                for (int j = 0; j < 4; ++j) {
                    float vr = r1[j] + (&biR.x)[j] + r2[j] + (&bhR.x)[j];
                    float vz = r1[4 + j] + (&biZ.x)[j] + r2[4 + j] + (&bhZ.x)[j];
                    float rg = 1.f / (1.f + __expf(-vr));
                    float zg = 1.f / (1.f + __expf(-vz));
                    float ht = tanhf(r1[8 + j] + (&biN.x)[j] + rg * (r2[8 + j] + (&bhN.x)[j]));
                    float hpv = (j == 0) ? hp0 : (j == 1) ? hp1 : (j == 2) ? hp2 : hp3;
                    hn_[j] = zg * hpv + (1.f - zg) * ht;
                }
                hp0 = hn_[0]; hp1 = hn_[1]; hp2 = hn_[2]; hp3 = hn_[3];
                unsigned long long hi_ = 0;
#pragma unroll
                for (int j = 0; j < 4; ++j)
                    hi_ |= (unsigned long long)f2bf_rne(hn_[j]) << (16 * j);
                // state store FIRST (must be IC-visible before arrival);
                // out stores after (may stay in flight past the drain)
                unsigned short* dst = hst + (size_t)(2 + ((s - 1) & 1)) * 32768
                                    + (size_t)(b >> 4) * 16384 + prodoff;
                __hip_atomic_store((unsigned long long*)dst, hi_,
                                   __ATOMIC_RELAXED, __HIP_MEMORY_SCOPE_AGENT);
                *(float4*)(out + ((size_t)b * L_ + t) * H_ + u0) =
                    make_float4(hn_[0], hn_[1], hn_[2], hn_[3]);
                if (t == L_ - 1)
                    *(float4*)(out + (size_t)B_ * L_ * H_ + (size_t)B_ * H_ + b * H_ + u0) =
                        make_float4(hn_[0], hn_[1], hn_[2], hn_[3]);
            }
#pragma unroll
            for (int j = 0; j < 16; ++j) { r1[j] = 0.f; r2[j] = 0.f; }
        }

        // ---- grid barrier (round-8 pattern, proven stable) -----------------
        if (s < L_) {
            // drain: state sc-store must be at IC; wave1's trailing out-store
            // (issued after the state store; vmcnt completes in order, m135)
            // may remain in flight.
            if (wave == 1) {
                asm volatile("s_waitcnt vmcnt(1)" ::: "memory");
            } else {
                asm volatile("s_waitcnt vmcnt(0)" ::: "memory");
            }
            __syncthreads();
            if (tid == 0) {
                const int g = grp >> 5;        // 8 groups of 32 blocks
                __hip_atomic_fetch_add(&bar[g * 256], 1u,
                                       __ATOMIC_RELAXED, __HIP_MEMORY_SCOPE_AGENT);
                if ((grp & 31) == 0) {
                    while (__hip_atomic_load(&bar[g * 256], __ATOMIC_RELAXED,
                                             __HIP_MEMORY_SCOPE_AGENT)
                           < (unsigned)(s + 1) * 32u)
                        __builtin_amdgcn_s_sleep(2);
                    __hip_atomic_fetch_add(&bar[4096], 1u,
                                           __ATOMIC_RELAXED, __HIP_MEMORY_SCOPE_AGENT);
                }
                while (__hip_atomic_load(&bar[4096], __ATOMIC_RELAXED,
                                         __HIP_MEMORY_SCOPE_AGENT)
                       < (unsigned)(s + 1) * 8u)
                    __builtin_amdgcn_s_sleep(2);
            }
            __syncthreads();
        }
    }
#undef ISSUE
#undef MFMA_GRP
}

extern "C" void kernel_launch(void* const* d_in, const int* in_sizes, int n_in,
                              void* d_out, int out_size, void* d_ws, size_t ws_size,
                              hipStream_t stream) {
    const float* x  = (const float*)d_in[0];
    const float* Wi = (const float*)d_in[1];
    const float* bi = (const float*)d_in[2];
    const float* Wh = (const float*)d_in[3];
    const float* bh = (const float*)d_in[4];
    float* out = (float*)d_out;
    char* ws = (char*)d_ws;

    // ws layout (bytes):
    //  [0, 48MB)              wt: 4 mats x {hi,lo} x [3072][1024] bf16
    //  [50331648, +256KB)     hst: 4 regions x 32768 bf16 (h0 s0/s1, h1 s0/s1)
    //  [50855936, +512KB)     bar: barrier counters (spread 1KB apart)
    //  [51380224, +384MB)     gi0: f32 [L][B][3H]
    unsigned short* wt  = (unsigned short*)(ws);
    unsigned short* hst = (unsigned short*)(ws + 50331648);
    unsigned int*   bar = (unsigned int*)(ws + 50855936);
    float*          gi0 = (float*)(ws + 51380224);

    hipMemsetAsync(ws + 50331648, 0, 1048576, stream);
    k_trans_w<<<dim3(768, 4), 256, 0, stream>>>(Wi, Wh, wt);
    k_gi0<<<dim3(512, 48), 512, 0, stream>>>(x, wt, gi0);

    void* args[] = {&wt, &gi0, &bi, &bh, &hst, &bar, &out};
    hipLaunchCooperativeKernel((void*)k_gru_pers, dim3(NBLK), dim3(512), args, 0, stream);
}